// Round 6
// baseline (852.560 us; speedup 1.0000x reference)
//
#include <hip/hip_runtime.h>
#include <math.h>

#define NROWS 16384
#define DIN   384
#define DIM   512
#define KSEL  6
#define NSPLIT 4
#define COLS_PER_SPLIT (NROWS / NSPLIT)   // 4096
#define ATT_SCALE 0.044194173824159216f   // 512^-0.5

typedef unsigned short u16;
typedef __attribute__((ext_vector_type(8))) short bf16x8;
typedef __attribute__((ext_vector_type(16))) float f32x16;

static __device__ __forceinline__ float lrelu_f(float v) {
  return v > 0.f ? v : 0.01f * v;
}

static __device__ __forceinline__ u16 f2bf(float f) {  // RNE f32->bf16
  unsigned u = __float_as_uint(f);
  unsigned r = (u + 0x7FFFu + ((u >> 16) & 1u)) >> 16;
  return (u16)r;
}

static __device__ __forceinline__ void sbar() {
  asm volatile("" ::: "memory");
  __builtin_amdgcn_s_barrier();
  asm volatile("" ::: "memory");
}

// ---------------------------------------------------------------------------
// small elementwise kernels
// ---------------------------------------------------------------------------
__global__ __launch_bounds__(256)
void convx(const float* __restrict__ X, u16* __restrict__ Xb) {
  int i = blockIdx.x * 256 + threadIdx.x;           // 8-elem chunk
  const float4* p = (const float4*)X + (size_t)i * 2;
  float4 a = p[0], b = p[1];
  uint4 o;
  o.x = f2bf(a.x) | ((unsigned)f2bf(a.y) << 16);
  o.y = f2bf(a.z) | ((unsigned)f2bf(a.w) << 16);
  o.z = f2bf(b.x) | ((unsigned)f2bf(b.y) << 16);
  o.w = f2bf(b.z) | ((unsigned)f2bf(b.w) << 16);
  ((uint4*)Xb)[i] = o;
}

__global__ __launch_bounds__(256)
void wconv(const float* __restrict__ W, u16* __restrict__ Wt, int K, int N) {
  int t = blockIdx.x * 256 + threadIdx.x;
  if (t >= K * N) return;
  int k = t / N, n = t - k * N;
  Wt[(size_t)n * K + k] = f2bf(W[t]);
}

__global__ __launch_bounds__(256)
void colsum_partial(const float* __restrict__ H, float* __restrict__ part) {
  int col = blockIdx.x * 64 + (threadIdx.x & 63);
  int sub = threadIdx.x >> 6;
  int rEnd = blockIdx.y * 512 + 512;
  float s = 0.f;
  for (int r = blockIdx.y * 512 + sub; r < rEnd; r += 4)
    s += H[(size_t)r * DIM + col];
  __shared__ float sh[4][64];
  sh[sub][threadIdx.x & 63] = s;
  __syncthreads();
  if (threadIdx.x < 64) {
    float tot = sh[0][threadIdx.x] + sh[1][threadIdx.x] +
                sh[2][threadIdx.x] + sh[3][threadIdx.x];
    part[(size_t)blockIdx.y * DIM + col] = tot;
  }
}

__global__ void finalize_mean(const float* __restrict__ part,
                              float* __restrict__ mean) {
  int c = threadIdx.x;
  float s = 0.f;
  for (int j = 0; j < 32; j++) s += part[j * DIM + c];
  mean[c] = s * (1.0f / NROWS);
}

// h = (h0 + mean)*0.5, bf16 output only
__global__ __launch_bounds__(256)
void h_fix_bf(const float* __restrict__ H0, const float* __restrict__ mean,
              u16* __restrict__ Hb) {
  int idx = blockIdx.x * 256 + threadIdx.x;         // 8-elem chunk
  int c = (idx * 8) & (DIM - 1);
  const float4* p = (const float4*)H0 + (size_t)idx * 2;
  float4 a = p[0], b = p[1];
  float4 m0 = *(const float4*)(mean + c);
  float4 m1 = *(const float4*)(mean + c + 4);
  a.x = (a.x + m0.x) * 0.5f; a.y = (a.y + m0.y) * 0.5f;
  a.z = (a.z + m0.z) * 0.5f; a.w = (a.w + m0.w) * 0.5f;
  b.x = (b.x + m1.x) * 0.5f; b.y = (b.y + m1.y) * 0.5f;
  b.z = (b.z + m1.z) * 0.5f; b.w = (b.w + m1.w) * 0.5f;
  uint4 o;
  o.x = f2bf(a.x) | ((unsigned)f2bf(a.y) << 16);
  o.y = f2bf(a.z) | ((unsigned)f2bf(a.w) << 16);
  o.z = f2bf(b.x) | ((unsigned)f2bf(b.y) << 16);
  o.w = f2bf(b.z) | ((unsigned)f2bf(b.w) << 16);
  ((uint4*)Hb)[idx] = o;
}

// ---------------------------------------------------------------------------
// bf16 MFMA GEMM: C[M=16384, N] = act(A[M,K]bf16 @ Wt[N,K]^T + bias), opt +=,
// opt bf16 dual-store (scaled). Tile 128x128, BK=64, 4 waves (2x2), each wave
// 2 mfrag x 2 nfrag of 32x32x16. (unchanged this round)
// ---------------------------------------------------------------------------
template<int ACT, int ACCUM, int STOREBF>
__global__ __launch_bounds__(256, 2)
void gemm_bf16(const u16* __restrict__ A, const u16* __restrict__ Wt,
               const float* __restrict__ bias, float* __restrict__ C,
               u16* __restrict__ Cb, float bscale, int K, int N) {
  __shared__ char lds[65536];   // A dbuf [0,32K), W dbuf [32K,64K)
  const int tid = threadIdx.x;
  const int w = tid >> 6, l = tid & 63;
  const int l31 = l & 31, lh = l >> 5, lh16 = lh << 4;
  const int qg = w & 1, ng = w >> 1;
  const int swz = (l31 & 7) << 4;
  const int rowBase = blockIdx.y * 128;
  const int colBase = blockIdx.x * 128;
  const int nsteps = K >> 6;

  f32x16 z;
  #pragma unroll
  for (int i = 0; i < 16; i++) z[i] = 0.f;
  f32x16 acc00 = z, acc01 = z, acc10 = z, acc11 = z;

#define GSTAGE(buf_, kc_) do { \
    const int r_ = tid >> 3, j_ = tid & 7; \
    const int js_ = ((j_ ^ (r_ & 7)) << 3); \
    const u16* as_ = A + (size_t)rowBase * K + (kc_); \
    const u16* ws_ = Wt + (size_t)colBase * K + (kc_); \
    char* ab_ = lds + (buf_) * 16384; \
    char* wb_ = lds + 32768 + (buf_) * 16384; \
    _Pragma("unroll") \
    for (int p_ = 0; p_ < 4; ++p_) { \
      __builtin_amdgcn_global_load_lds( \
        (const __attribute__((address_space(1))) void*)(as_ + (size_t)(r_ + 32 * p_) * K + js_), \
        (__attribute__((address_space(3))) void*)(ab_ + w * 1024 + p_ * 4096), 16, 0, 0); \
      __builtin_amdgcn_global_load_lds( \
        (const __attribute__((address_space(1))) void*)(ws_ + (size_t)(r_ + 32 * p_) * K + js_), \
        (__attribute__((address_space(3))) void*)(wb_ + w * 1024 + p_ * 4096), 16, 0, 0); \
    } \
  } while (0)

  GSTAGE(0, 0);
  asm volatile("s_waitcnt vmcnt(0)" ::: "memory");
  sbar();
  #pragma unroll 1
  for (int s = 0; s < nsteps; ++s) {
    const int cur = s & 1;
    if (s + 1 < nsteps) GSTAGE(cur ^ 1, (s + 1) * 64);
    __builtin_amdgcn_sched_barrier(0);
    const char* ab = lds + cur * 16384;
    const char* wb = lds + 32768 + cur * 16384;
    __builtin_amdgcn_s_setprio(1);
    #pragma unroll
    for (int s4 = 0; s4 < 4; ++s4) {
      const int off = (s4 * 32 + lh16) ^ swz;
      bf16x8 am0 = *(const bf16x8*)(ab + (qg * 64 + l31) * 128 + off);
      bf16x8 am1 = *(const bf16x8*)(ab + (qg * 64 + 32 + l31) * 128 + off);
      bf16x8 wn0 = *(const bf16x8*)(wb + (ng * 64 + l31) * 128 + off);
      bf16x8 wn1 = *(const bf16x8*)(wb + (ng * 64 + 32 + l31) * 128 + off);
      acc00 = __builtin_amdgcn_mfma_f32_32x32x16_bf16(wn0, am0, acc00, 0, 0, 0);
      acc01 = __builtin_amdgcn_mfma_f32_32x32x16_bf16(wn1, am0, acc01, 0, 0, 0);
      acc10 = __builtin_amdgcn_mfma_f32_32x32x16_bf16(wn0, am1, acc10, 0, 0, 0);
      acc11 = __builtin_amdgcn_mfma_f32_32x32x16_bf16(wn1, am1, acc11, 0, 0, 0);
    }
    __builtin_amdgcn_s_setprio(0);
    asm volatile("s_waitcnt vmcnt(0)" ::: "memory");
    sbar();
  }
#undef GSTAGE

  // epilogue: spill to LDS (XOR-swizzled cols), then coalesced store
  float* Ls = (float*)lds;
  {
    const int m0 = qg * 64 + l31;
    const int k0 = (m0 & 7) << 2;
    #pragma unroll
    for (int r = 0; r < 16; ++r) {
      const int nd = ng * 64 + (r & 3) + 8 * (r >> 2) + 4 * lh;
      Ls[m0 * 128 + (nd ^ k0)] = acc00[r];
      Ls[m0 * 128 + ((nd + 32) ^ k0)] = acc01[r];
      Ls[(m0 + 32) * 128 + (nd ^ k0)] = acc10[r];
      Ls[(m0 + 32) * 128 + ((nd + 32) ^ k0)] = acc11[r];
    }
  }
  sbar();
  #pragma unroll
  for (int p = 0; p < 16; ++p) {
    int idx = tid + 256 * p;
    int m = idx >> 5, c4 = (idx & 31) << 2;
    float4 v = *(const float4*)&Ls[m * 128 + (c4 ^ ((m & 7) << 2))];
    int col = colBase + c4;
    float4 bv = *(const float4*)&bias[col];
    v.x += bv.x; v.y += bv.y; v.z += bv.z; v.w += bv.w;
    if (ACT) {
      v.x = lrelu_f(v.x); v.y = lrelu_f(v.y);
      v.z = lrelu_f(v.z); v.w = lrelu_f(v.w);
    }
    size_t o = (size_t)(rowBase + m) * N + col;
    if (ACCUM) {
      float4 c0 = *(const float4*)&C[o];
      v.x += c0.x; v.y += c0.y; v.z += c0.z; v.w += c0.w;
    }
    *(float4*)&C[o] = v;
    if (STOREBF) {
      ushort4 q;
      q.x = f2bf(v.x * bscale); q.y = f2bf(v.y * bscale);
      q.z = f2bf(v.z * bscale); q.w = f2bf(v.w * bscale);
      *(ushort4*)&Cb[o] = q;
    }
  }
}

// ---------------------------------------------------------------------------
// MFMA attn-logit + per-row top-6. Counted-vmcnt (T4) triple-buffer pipeline.
// 512 blocks, 512 thr (8 waves), 1 block/CU (144 KB LDS). XCD decode (R5,
// FETCH-verified): xcd=bid&7, local=bid>>3, split=local&3,
// rowBase=(xcd*16+(local>>2))*128 -> per-XCD A = 2 MB (L2-resident).
// Tile 128q x 256n, BK=64. Waves: qg=w&1 (2x64q), ng=w>>1 (4x64n); per wave
// 2qf x 2nf of 32x32x16, swapped operands mfma(neighbor, query, acc):
// lane&31 = query row -> in-register top-6, no score spill.
// Pipeline: STAGE(s+2) -> MFMA(buf s%3) -> [T6] -> s_waitcnt vmcnt(6) -> bar.
// Loads have ~2 MFMA phases to land; drain-0 only at the tail.
// ---------------------------------------------------------------------------
#define T6(tv, tix, vv, cc) do { float v_ = (vv); \
  if (v_ > tv[5]) { tv[5] = v_; tix[5] = (cc); \
    if (tv[5] > tv[4]) { float t=tv[4];tv[4]=tv[5];tv[5]=t; int q=tix[4];tix[4]=tix[5];tix[5]=q; } \
    if (tv[4] > tv[3]) { float t=tv[3];tv[3]=tv[4];tv[4]=t; int q=tix[3];tix[3]=tix[4];tix[4]=q; } \
    if (tv[3] > tv[2]) { float t=tv[2];tv[2]=tv[3];tv[3]=t; int q=tix[2];tix[2]=tix[3];tix[3]=q; } \
    if (tv[2] > tv[1]) { float t=tv[1];tv[1]=tv[2];tv[2]=t; int q=tix[1];tix[1]=tix[2];tix[2]=q; } \
    if (tv[1] > tv[0]) { float t=tv[0];tv[0]=tv[1];tv[1]=t; int q=tix[0];tix[0]=tix[1];tix[1]=q; } \
  } } while (0)

__global__ __launch_bounds__(512, 1)
void attn_topk_mfma(const u16* __restrict__ EHb, const u16* __restrict__ ETb,
                    float* __restrict__ TWp, int* __restrict__ TIp) {
  __shared__ char lds[147456];  // 3 buffers x (A 16K + B 32K)
  const int tid = threadIdx.x;
  const int w = tid >> 6, l = tid & 63;
  const int l31 = l & 31, lh = l >> 5, lh16 = lh << 4;
  const int qg = w & 1, ng = w >> 1;           // qg 0..1, ng 0..3
  const int swz = (l31 & 7) << 4;

  const int bid = blockIdx.x;
  const int xcd = bid & 7;
  const int local = bid >> 3;
  const int split = local & 3;
  const int rowBase = (xcd * 16 + (local >> 2)) * 128;

  f32x16 z;
  #pragma unroll
  for (int i = 0; i < 16; i++) z[i] = 0.f;
  f32x16 acc00 = z, acc01 = z, acc10 = z, acc11 = z;

  float tvA[KSEL], tvB[KSEL]; int tixA[KSEL], tixB[KSEL];
  #pragma unroll
  for (int k = 0; k < KSEL; k++) {
    tvA[k] = -INFINITY; tixA[k] = 0; tvB[k] = -INFINITY; tixB[k] = 0;
  }

  // 6 global_load_lds per thread/wave per STAGE (A:2, B:4) -> vmcnt unit = 6
#define STAGE(bufi_, ns_) do { \
    const int ct_ = (ns_) >> 3, kc_ = (ns_) & 7; \
    const int r_ = tid >> 3, j_ = tid & 7; \
    const int js_ = ((j_ ^ (r_ & 7)) << 3); \
    const u16* as_ = EHb + (size_t)rowBase * DIM + kc_ * 64; \
    const u16* bs_ = ETb + (size_t)(split * COLS_PER_SPLIT + ct_ * 256) * DIM + kc_ * 64; \
    char* ab_ = lds + (bufi_) * 49152; \
    char* bb_ = ab_ + 16384; \
    _Pragma("unroll") \
    for (int p_ = 0; p_ < 2; ++p_) { \
      __builtin_amdgcn_global_load_lds( \
        (const __attribute__((address_space(1))) void*)(as_ + (size_t)(r_ + 64 * p_) * DIM + js_), \
        (__attribute__((address_space(3))) void*)(ab_ + (tid + 512 * p_) * 16), 16, 0, 0); \
    } \
    _Pragma("unroll") \
    for (int p_ = 0; p_ < 4; ++p_) { \
      __builtin_amdgcn_global_load_lds( \
        (const __attribute__((address_space(1))) void*)(bs_ + (size_t)(r_ + 64 * p_) * DIM + js_), \
        (__attribute__((address_space(3))) void*)(bb_ + (tid + 512 * p_) * 16), 16, 0, 0); \
    } \
  } while (0)

  int cur = 0, stg = 2;
  STAGE(0, 0);
  STAGE(1, 1);
  asm volatile("s_waitcnt vmcnt(6)" ::: "memory");   // buf0 complete
  sbar();
  #pragma unroll 1
  for (int s = 0; s < 128; ++s) {                    // 16 ct x 8 kc
    if (s + 2 < 128) STAGE(stg, s + 2);
    __builtin_amdgcn_sched_barrier(0);
    const char* ab = lds + cur * 49152;
    const char* bb = ab + 16384;
    __builtin_amdgcn_s_setprio(1);
    #pragma unroll
    for (int s4 = 0; s4 < 4; ++s4) {
      const int off = (s4 * 32 + lh16) ^ swz;
      bf16x8 aq0 = *(const bf16x8*)(ab + (qg * 64 + l31) * 128 + off);
      bf16x8 aq1 = *(const bf16x8*)(ab + (qg * 64 + 32 + l31) * 128 + off);
      bf16x8 bn0 = *(const bf16x8*)(bb + (ng * 64 + l31) * 128 + off);
      bf16x8 bn1 = *(const bf16x8*)(bb + (ng * 64 + 32 + l31) * 128 + off);
      acc00 = __builtin_amdgcn_mfma_f32_32x32x16_bf16(bn0, aq0, acc00, 0, 0, 0);
      acc01 = __builtin_amdgcn_mfma_f32_32x32x16_bf16(bn1, aq0, acc01, 0, 0, 0);
      acc10 = __builtin_amdgcn_mfma_f32_32x32x16_bf16(bn0, aq1, acc10, 0, 0, 0);
      acc11 = __builtin_amdgcn_mfma_f32_32x32x16_bf16(bn1, aq1, acc11, 0, 0, 0);
    }
    __builtin_amdgcn_s_setprio(0);
    if ((s & 7) == 7) {                      // end of K for tile ct = s>>3
      const int cb = split * COLS_PER_SPLIT + (s >> 3) * 256 + ng * 64 + 4 * lh;
      #pragma unroll
      for (int r = 0; r < 16; ++r) {
        const int nd = cb + (r & 3) + 8 * (r >> 2);
        T6(tvA, tixA, acc00[r], nd);
        T6(tvB, tixB, acc10[r], nd);
      }
      #pragma unroll
      for (int r = 0; r < 16; ++r) {
        const int nd = cb + 32 + (r & 3) + 8 * (r >> 2);
        T6(tvA, tixA, acc01[r], nd);
        T6(tvB, tixB, acc11[r], nd);
      }
      acc00 = z; acc01 = z; acc10 = z; acc11 = z;
    }
    if (s < 126) { asm volatile("s_waitcnt vmcnt(6)" ::: "memory"); }
    else         { asm volatile("s_waitcnt vmcnt(0)" ::: "memory"); }
    sbar();
    cur = (cur == 2) ? 0 : cur + 1;
    stg = (stg == 2) ? 0 : stg + 1;
  }
#undef STAGE

  // merge 8 partial lists per query row (ng x lh)
  float* MV = (float*)lds;
  int* MI = (int*)(lds + 24576);
  {
    const int src = ng * 2 + lh;                 // 0..7
    const int q0 = qg * 64 + l31;                // 0..95; +32 -> up to 127
    #pragma unroll
    for (int k = 0; k < KSEL; k++) {
      MV[(q0 * 8 + src) * 6 + k] = tvA[k];
      MI[(q0 * 8 + src) * 6 + k] = tixA[k];
      MV[((q0 + 32) * 8 + src) * 6 + k] = tvB[k];
      MI[((q0 + 32) * 8 + src) * 6 + k] = tixB[k];
    }
  }
  sbar();
  if (tid < 128) {
    int mb = tid * 48;
    unsigned long long used = 0ull;
    float ov[KSEL]; int oi[KSEL];
    #pragma unroll
    for (int s = 0; s < KSEL; ++s) {
      float bvv = -INFINITY; int bi = 0x7fffffff; int be = 0;
      for (int e = 0; e < 48; ++e) {
        if (used & (1ull << e)) continue;
        float v = MV[mb + e]; int ix = MI[mb + e];
        if (v > bvv || (v == bvv && ix < bi)) { bvv = v; bi = ix; be = e; }
      }
      used |= 1ull << be;
      ov[s] = bvv; oi[s] = bi;
    }
    size_t o = ((size_t)split * NROWS + rowBase + tid) * KSEL;
    #pragma unroll
    for (int k = 0; k < KSEL; k++) { TWp[o + k] = ov[k]; TIp[o + k] = oi[k]; }
  }
}

// Merge NSPLIT per-split top-6 lists into global top-6 (value desc, idx asc).
__global__ __launch_bounds__(256)
void topk_merge(const float* __restrict__ TWp, const int* __restrict__ TIp,
                float* __restrict__ TW, int* __restrict__ TI) {
  int row = blockIdx.x * 256 + threadIdx.x;
  float tv[KSEL]; int tix[KSEL];
  #pragma unroll
  for (int k = 0; k < KSEL; k++) { tv[k] = -INFINITY; tix[k] = 0x7fffffff; }
  #pragma unroll
  for (int s = 0; s < NSPLIT; s++) {
    size_t o = ((size_t)s * NROWS + row) * KSEL;
    #pragma unroll
    for (int k = 0; k < KSEL; k++) {
      float cv = TWp[o + k]; int ci = TIp[o + k];
      bool better5 = (cv > tv[5]) || (cv == tv[5] && ci < tix[5]);
      if (better5) {
        tv[5] = cv; tix[5] = ci;
        if ((tv[5] > tv[4]) || (tv[5] == tv[4] && tix[5] < tix[4])) {
          float t = tv[4]; tv[4] = tv[5]; tv[5] = t;
          int ti = tix[4]; tix[4] = tix[5]; tix[5] = ti; }
        if ((tv[4] > tv[3]) || (tv[4] == tv[3] && tix[4] < tix[3])) {
          float t = tv[3]; tv[3] = tv[4]; tv[4] = t;
          int ti = tix[3]; tix[3] = tix[4]; tix[4] = ti; }
        if ((tv[3] > tv[2]) || (tv[3] == tv[2] && tix[3] < tix[2])) {
          float t = tv[2]; tv[2] = tv[3]; tv[3] = t;
          int ti = tix[2]; tix[2] = tix[3]; tix[3] = ti; }
        if ((tv[2] > tv[1]) || (tv[2] == tv[1] && tix[2] < tix[1])) {
          float t = tv[1]; tv[1] = tv[2]; tv[2] = t;
          int ti = tix[1]; tix[1] = tix[2]; tix[2] = ti; }
        if ((tv[1] > tv[0]) || (tv[1] == tv[0] && tix[1] < tix[0])) {
          float t = tv[0]; tv[0] = tv[1]; tv[1] = t;
          int ti = tix[0]; tix[0] = tix[1]; tix[1] = ti; }
      }
    }
  }
  size_t o = (size_t)row * KSEL;
  #pragma unroll
  for (int k = 0; k < KSEL; k++) { TW[o + k] = tv[k]; TI[o + k] = tix[k]; }
}

// ---------------------------------------------------------------------------
// Neighbor aggregation. One wave per row; writes bf16 s_in / b_in.
// ---------------------------------------------------------------------------
__global__ __launch_bounds__(256)
void neighbor_kernel(const float* __restrict__ EH, const float* __restrict__ ET,
                     const float* __restrict__ TW, const int* __restrict__ TI,
                     u16* __restrict__ SINb, u16* __restrict__ BINb) {
  const int lane = threadIdx.x & 63;
  const int row = blockIdx.x * 4 + (threadIdx.x >> 6);
  const float* eh = EH + (size_t)row * DIM;
  float ehv[8];
  #pragma unroll
  for (int u = 0; u < 8; u++) ehv[u] = eh[u * 64 + lane];
  float tw[KSEL]; int ti[KSEL];
  #pragma unroll
  for (int k = 0; k < KSEL; k++) {
    tw[k] = TW[(size_t)row * KSEL + k];
    ti[k] = TI[(size_t)row * KSEL + k];
  }
  float m = tw[0];
  #pragma unroll
  for (int k = 1; k < KSEL; k++) m = fmaxf(m, tw[k]);
  float p[KSEL], ps = 0.f;
  #pragma unroll
  for (int k = 0; k < KSEL; k++) { p[k] = expf(tw[k] - m); ps += p[k]; }
  float inv = 1.f / ps;
  #pragma unroll
  for (int k = 0; k < KSEL; k++) p[k] *= inv;

  float nb[KSEL][8];
  float kaw[KSEL];
  #pragma unroll
  for (int k = 0; k < KSEL; k++) {
    const float* et = ET + (size_t)ti[k] * DIM;
    float snb = 0.f, sg = 0.f;
    #pragma unroll
    for (int u = 0; u < 8; u++) {
      float nbv = et[u * 64 + lane];
      nb[k][u] = nbv;
      float ehr = p[k] * nbv + (1.f - p[k]) * ehv[u];
      float g = tanhf(ehv[u] + ehr);
      snb += nbv; sg += g;
    }
    #pragma unroll
    for (int off = 32; off > 0; off >>= 1) {
      snb += __shfl_xor(snb, off);
      sg  += __shfl_xor(sg, off);
    }
    kaw[k] = snb * sg;
  }
  float km = kaw[0];
  #pragma unroll
  for (int k = 1; k < KSEL; k++) km = fmaxf(km, kaw[k]);
  float kp[KSEL], ks = 0.f;
  #pragma unroll
  for (int k = 0; k < KSEL; k++) { kp[k] = expf(kaw[k] - km); ks += kp[k]; }
  float kinv = 1.f / ks;
  #pragma unroll
  for (int k = 0; k < KSEL; k++) kp[k] *= kinv;

  #pragma unroll
  for (int u = 0; u < 8; u++) {
    float enh = 0.f;
    #pragma unroll
    for (int k = 0; k < KSEL; k++) enh += kp[k] * nb[k][u];
    size_t o = (size_t)row * DIM + u * 64 + lane;
    SINb[o] = f2bf(ehv[u] + enh);
    BINb[o] = f2bf(ehv[u] * enh);
  }
}

__global__ __launch_bounds__(256)
void att2_kernel(const float* __restrict__ HID, const float* __restrict__ w2,
                 const float* __restrict__ b2, float* __restrict__ ASC) {
  const int lane = threadIdx.x & 63;
  const int row = blockIdx.x * 4 + (threadIdx.x >> 6);
  float4 hv = ((const float4*)(HID + (size_t)row * 256))[lane];
  float4 wv = ((const float4*)w2)[lane];
  float s = hv.x * wv.x + hv.y * wv.y + hv.z * wv.z + hv.w * wv.w;
  #pragma unroll
  for (int off = 32; off > 0; off >>= 1) s += __shfl_xor(s, off);
  if (lane == 0) ASC[row] = s + b2[0];
}

__global__ __launch_bounds__(1024)
void areduce(const float* __restrict__ ASC, float* __restrict__ stats) {
  __shared__ float sm[1024];
  int t = threadIdx.x;
  float m = -INFINITY;
  for (int i = t; i < NROWS; i += 1024) m = fmaxf(m, ASC[i]);
  sm[t] = m; __syncthreads();
  for (int s = 512; s > 0; s >>= 1) {
    if (t < s) sm[t] = fmaxf(sm[t], sm[t + s]);
    __syncthreads();
  }
  float mx = sm[0]; __syncthreads();
  float sum = 0.f;
  for (int i = t; i < NROWS; i += 1024) sum += expf(ASC[i] - mx);
  sm[t] = sum; __syncthreads();
  for (int s = 512; s > 0; s >>= 1) {
    if (t < s) sm[t] += sm[t + s];
    __syncthreads();
  }
  if (t == 0) { stats[0] = mx; stats[1] = sm[0]; }
}

__global__ __launch_bounds__(256)
void pooled_partial(const float* __restrict__ EMB, const float* __restrict__ ASC,
                    const float* __restrict__ stats, float* __restrict__ part) {
  int col = blockIdx.x * 64 + (threadIdx.x & 63);
  int sub = threadIdx.x >> 6;
  float mx = stats[0];
  int rEnd = blockIdx.y * 512 + 512;
  float s = 0.f;
  for (int r = blockIdx.y * 512 + sub; r < rEnd; r += 4)
    s += expf(ASC[r] - mx) * EMB[(size_t)r * DIM + col];
  __shared__ float sh[4][64];
  sh[sub][threadIdx.x & 63] = s;
  __syncthreads();
  if (threadIdx.x < 64) {
    float tot = sh[0][threadIdx.x] + sh[1][threadIdx.x] +
                sh[2][threadIdx.x] + sh[3][threadIdx.x];
    part[(size_t)blockIdx.y * DIM + col] = tot;
  }
}

__global__ __launch_bounds__(512)
void final_kernel(const float* __restrict__ part, const float* __restrict__ stats,
                  const float* __restrict__ ln_g, const float* __restrict__ ln_b,
                  const float* __restrict__ fc_w, const float* __restrict__ fc_b,
                  float* __restrict__ out) {
  __shared__ float sh[512];
  int t = threadIdx.x;
  float s = 0.f;
  for (int j = 0; j < 32; j++) s += part[j * DIM + t];
  float pooled = s / stats[1];
  sh[t] = pooled; __syncthreads();
  for (int off = 256; off > 0; off >>= 1) {
    if (t < off) sh[t] += sh[t + off];
    __syncthreads();
  }
  float mu = sh[0] * (1.f / DIM); __syncthreads();
  float dv = pooled - mu;
  sh[t] = dv * dv; __syncthreads();
  for (int off = 256; off > 0; off >>= 1) {
    if (t < off) sh[t] += sh[t + off];
    __syncthreads();
  }
  float var = sh[0] * (1.f / DIM); __syncthreads();
  float normed = dv * rsqrtf(var + 1e-5f) * ln_g[t] + ln_b[t];
  sh[t] = normed * fc_w[t * 2 + 0]; __syncthreads();
  for (int off = 256; off > 0; off >>= 1) {
    if (t < off) sh[t] += sh[t + off];
    __syncthreads();
  }
  float l0 = sh[0] + fc_b[0]; __syncthreads();
  sh[t] = normed * fc_w[t * 2 + 1]; __syncthreads();
  for (int off = 256; off > 0; off >>= 1) {
    if (t < off) sh[t] += sh[t + off];
    __syncthreads();
  }
  float l1 = sh[0] + fc_b[1];
  if (t == 0) {
    float mm = fmaxf(l0, l1);
    float e0 = expf(l0 - mm), e1 = expf(l1 - mm);
    float si = 1.f / (e0 + e1);
    out[0] = l0; out[1] = l1; out[2] = e0 * si; out[3] = e1 * si;
  }
}

// ---------------------------------------------------------------------------
extern "C" void kernel_launch(void* const* d_in, const int* in_sizes, int n_in,
                              void* d_out, int out_size, void* d_ws, size_t ws_size,
                              hipStream_t stream) {
  (void)in_sizes; (void)n_in; (void)out_size; (void)ws_size;
  const float* x      = (const float*)d_in[0];
  const float* fc1_w  = (const float*)d_in[1];
  const float* fc1_b  = (const float*)d_in[2];
  const float* wh_w   = (const float*)d_in[3];
  const float* wh_b   = (const float*)d_in[4];
  const float* wt_w   = (const float*)d_in[5];
  const float* wt_b   = (const float*)d_in[6];
  const float* lin1_w = (const float*)d_in[7];
  const float* lin1_b = (const float*)d_in[8];
  const float* lin2_w = (const float*)d_in[9];
  const float* lin2_b = (const float*)d_in[10];
  const float* att1_w = (const float*)d_in[11];
  const float* att1_b = (const float*)d_in[12];
  const float* att2_w = (const float*)d_in[13];
  const float* att2_b = (const float*)d_in[14];
  const float* ln_g   = (const float*)d_in[15];
  const float* ln_b   = (const float*)d_in[16];
  const float* fc_w   = (const float*)d_in[17];
  const float* fc_b   = (const float*)d_in[18];
  float* out = (float*)d_out;

  char* ws = (char*)d_ws;
  float* B0   = (float*)(ws);                       // h0 -> HID
  float* B1   = (float*)(ws + 33554432);            // [xb] -> e_h
  float* B2   = (float*)(ws + 67108864);            // e_t -> emb
  float* TWp  = (float*)(ws + 100663296);
  int*   TIp  = (int*)  (ws + 100663296 + 1572864);
  float* TW   = (float*)(ws + 100663296 + 3145728);
  int*   TI   = (int*)  (ws + 100663296 + 3145728 + 393216);
  float* part = (float*)(ws + 100663296 + 3145728 + 786432);
  float* mean = (float*)(ws + 100663296 + 3145728 + 786432 + 65536);
  float* ascr = (float*)(ws + 100663296 + 3145728 + 786432 + 65536 + 2048);
  float* stats= (float*)(ws + 100663296 + 3145728 + 786432 + 65536 + 2048 + 65536);
  u16*   hb   = (u16*)(ws + 104732672);             // -> embb
  u16*   EHb  = (u16*)(ws + 104732672 + 16777216);  // -> sinb
  u16*   ETb  = (u16*)(ws + 104732672 + 33554432);  // -> binb
  u16*   WT   = (u16*)(ws + 104732672 + 50331648);  // transposed bf16 weights
  u16* fc1t = WT;
  u16* wht  = fc1t + 196608;
  u16* wtt  = wht + 262144;
  u16* lin1t= wtt + 262144;
  u16* lin2t= lin1t + 262144;
  u16* att1t= lin2t + 262144;
  u16* xb   = (u16*)B1;      // temp in B1 region, dead before e_h written
  u16* sinb = EHb;           // reuse after attn
  u16* binb = ETb;
  u16* embb = hb;

  // 0. input + weight conversions (bf16, weights transposed to [N][K])
  convx<<<3072, 256, 0, stream>>>(x, xb);
  wconv<<<768, 256, 0, stream>>>(fc1_w, fc1t, 384, 512);
  wconv<<<1024, 256, 0, stream>>>(wh_w, wht, 512, 512);
  wconv<<<1024, 256, 0, stream>>>(wt_w, wtt, 512, 512);
  wconv<<<1024, 256, 0, stream>>>(lin1_w, lin1t, 512, 512);
  wconv<<<1024, 256, 0, stream>>>(lin2_w, lin2t, 512, 512);
  wconv<<<512, 256, 0, stream>>>(att1_w, att1t, 512, 256);
  // 1. h0 = lrelu(x @ fc1_w + b)
  gemm_bf16<1,0,0><<<dim3(4,128), 256, 0, stream>>>(xb, fc1t, fc1_b, B0, nullptr, 1.f, 384, 512);
  // 2-4. column mean; hb = bf16((h0+mean)*0.5)
  colsum_partial<<<dim3(8,32), 256, 0, stream>>>(B0, part);
  finalize_mean<<<1, 512, 0, stream>>>(part, mean);
  h_fix_bf<<<4096, 256, 0, stream>>>(B0, mean, hb);
  // 5-6. e_h (f32 + bf16*SCALE), e_t (f32 + bf16)
  gemm_bf16<0,0,1><<<dim3(4,128), 256, 0, stream>>>(hb, wht, wh_b, B1, EHb, ATT_SCALE, 512, 512);
  gemm_bf16<0,0,1><<<dim3(4,128), 256, 0, stream>>>(hb, wtt, wt_b, B2, ETb, 1.f, 512, 512);
  // 7. fused MFMA attn-logit + top-6 per split (counted-vmcnt), then merge
  attn_topk_mfma<<<512, 512, 0, stream>>>(EHb, ETb, TWp, TIp);
  topk_merge<<<64, 256, 0, stream>>>(TWp, TIp, TW, TI);
  // 8. neighbor aggregation -> bf16 s_in / b_in
  neighbor_kernel<<<4096, 256, 0, stream>>>(B1, B2, TW, TI, sinb, binb);
  // 9-10. emb = lrelu(s_in@lin1+b) + lrelu(b_in@lin2+b)  (f32 in B2 + bf16)
  gemm_bf16<1,0,0><<<dim3(4,128), 256, 0, stream>>>(sinb, lin1t, lin1_b, B2, nullptr, 1.f, 512, 512);
  gemm_bf16<1,1,1><<<dim3(4,128), 256, 0, stream>>>(binb, lin2t, lin2_b, B2, embb, 1.f, 512, 512);
  // 11. hidden = lrelu(emb@att1+b) -> B0 f32
  gemm_bf16<1,0,0><<<dim3(2,128), 256, 0, stream>>>(embb, att1t, att1_b, B0, nullptr, 1.f, 512, 256);
  // 12-15. readout
  att2_kernel<<<4096, 256, 0, stream>>>(B0, att2_w, att2_b, ascr);
  areduce<<<1, 1024, 0, stream>>>(ascr, stats);
  pooled_partial<<<dim3(8,32), 256, 0, stream>>>(B2, ascr, stats, part);
  final_kernel<<<1, 512, 0, stream>>>(part, stats, ln_g, ln_b, fc_w, fc_b, out);
}

// Round 7
// 667.061 us; speedup vs baseline: 1.2781x; 1.2781x over previous
//
#include <hip/hip_runtime.h>
#include <math.h>

#define NROWS 16384
#define DIN   384
#define DIM   512
#define KSEL  6
#define NSPLIT 4
#define COLS_PER_SPLIT (NROWS / NSPLIT)   // 4096
#define ATT_SCALE 0.044194173824159216f   // 512^-0.5

typedef unsigned short u16;
typedef __attribute__((ext_vector_type(8))) short bf16x8;
typedef __attribute__((ext_vector_type(16))) float f32x16;

static __device__ __forceinline__ float lrelu_f(float v) {
  return v > 0.f ? v : 0.01f * v;
}

static __device__ __forceinline__ u16 f2bf(float f) {  // RNE f32->bf16
  unsigned u = __float_as_uint(f);
  unsigned r = (u + 0x7FFFu + ((u >> 16) & 1u)) >> 16;
  return (u16)r;
}

static __device__ __forceinline__ void sbar() {
  asm volatile("" ::: "memory");
  __builtin_amdgcn_s_barrier();
  asm volatile("" ::: "memory");
}

// ---------------------------------------------------------------------------
// small elementwise kernels
// ---------------------------------------------------------------------------
__global__ __launch_bounds__(256)
void convx(const float* __restrict__ X, u16* __restrict__ Xb) {
  int i = blockIdx.x * 256 + threadIdx.x;           // 8-elem chunk
  const float4* p = (const float4*)X + (size_t)i * 2;
  float4 a = p[0], b = p[1];
  uint4 o;
  o.x = f2bf(a.x) | ((unsigned)f2bf(a.y) << 16);
  o.y = f2bf(a.z) | ((unsigned)f2bf(a.w) << 16);
  o.z = f2bf(b.x) | ((unsigned)f2bf(b.y) << 16);
  o.w = f2bf(b.z) | ((unsigned)f2bf(b.w) << 16);
  ((uint4*)Xb)[i] = o;
}

__global__ __launch_bounds__(256)
void wconv(const float* __restrict__ W, u16* __restrict__ Wt, int K, int N) {
  int t = blockIdx.x * 256 + threadIdx.x;
  if (t >= K * N) return;
  int k = t / N, n = t - k * N;
  Wt[(size_t)n * K + k] = f2bf(W[t]);
}

__global__ __launch_bounds__(256)
void colsum_partial(const float* __restrict__ H, float* __restrict__ part) {
  int col = blockIdx.x * 64 + (threadIdx.x & 63);
  int sub = threadIdx.x >> 6;
  int rEnd = blockIdx.y * 512 + 512;
  float s = 0.f;
  for (int r = blockIdx.y * 512 + sub; r < rEnd; r += 4)
    s += H[(size_t)r * DIM + col];
  __shared__ float sh[4][64];
  sh[sub][threadIdx.x & 63] = s;
  __syncthreads();
  if (threadIdx.x < 64) {
    float tot = sh[0][threadIdx.x] + sh[1][threadIdx.x] +
                sh[2][threadIdx.x] + sh[3][threadIdx.x];
    part[(size_t)blockIdx.y * DIM + col] = tot;
  }
}

__global__ void finalize_mean(const float* __restrict__ part,
                              float* __restrict__ mean) {
  int c = threadIdx.x;
  float s = 0.f;
  for (int j = 0; j < 32; j++) s += part[j * DIM + c];
  mean[c] = s * (1.0f / NROWS);
}

// h = (h0 + mean)*0.5, bf16 output only
__global__ __launch_bounds__(256)
void h_fix_bf(const float* __restrict__ H0, const float* __restrict__ mean,
              u16* __restrict__ Hb) {
  int idx = blockIdx.x * 256 + threadIdx.x;         // 8-elem chunk
  int c = (idx * 8) & (DIM - 1);
  const float4* p = (const float4*)H0 + (size_t)idx * 2;
  float4 a = p[0], b = p[1];
  float4 m0 = *(const float4*)(mean + c);
  float4 m1 = *(const float4*)(mean + c + 4);
  a.x = (a.x + m0.x) * 0.5f; a.y = (a.y + m0.y) * 0.5f;
  a.z = (a.z + m0.z) * 0.5f; a.w = (a.w + m0.w) * 0.5f;
  b.x = (b.x + m1.x) * 0.5f; b.y = (b.y + m1.y) * 0.5f;
  b.z = (b.z + m1.z) * 0.5f; b.w = (b.w + m1.w) * 0.5f;
  uint4 o;
  o.x = f2bf(a.x) | ((unsigned)f2bf(a.y) << 16);
  o.y = f2bf(a.z) | ((unsigned)f2bf(a.w) << 16);
  o.z = f2bf(b.x) | ((unsigned)f2bf(b.y) << 16);
  o.w = f2bf(b.z) | ((unsigned)f2bf(b.w) << 16);
  ((uint4*)Hb)[idx] = o;
}

// ---------------------------------------------------------------------------
// bf16 MFMA GEMM (unchanged): C = act(A@Wt^T + bias), opt +=, opt bf16 store.
// ---------------------------------------------------------------------------
template<int ACT, int ACCUM, int STOREBF>
__global__ __launch_bounds__(256, 2)
void gemm_bf16(const u16* __restrict__ A, const u16* __restrict__ Wt,
               const float* __restrict__ bias, float* __restrict__ C,
               u16* __restrict__ Cb, float bscale, int K, int N) {
  __shared__ char lds[65536];   // A dbuf [0,32K), W dbuf [32K,64K)
  const int tid = threadIdx.x;
  const int w = tid >> 6, l = tid & 63;
  const int l31 = l & 31, lh = l >> 5, lh16 = lh << 4;
  const int qg = w & 1, ng = w >> 1;
  const int swz = (l31 & 7) << 4;
  const int rowBase = blockIdx.y * 128;
  const int colBase = blockIdx.x * 128;
  const int nsteps = K >> 6;

  f32x16 z;
  #pragma unroll
  for (int i = 0; i < 16; i++) z[i] = 0.f;
  f32x16 acc00 = z, acc01 = z, acc10 = z, acc11 = z;

#define GSTAGE(buf_, kc_) do { \
    const int r_ = tid >> 3, j_ = tid & 7; \
    const int js_ = ((j_ ^ (r_ & 7)) << 3); \
    const u16* as_ = A + (size_t)rowBase * K + (kc_); \
    const u16* ws_ = Wt + (size_t)colBase * K + (kc_); \
    char* ab_ = lds + (buf_) * 16384; \
    char* wb_ = lds + 32768 + (buf_) * 16384; \
    _Pragma("unroll") \
    for (int p_ = 0; p_ < 4; ++p_) { \
      __builtin_amdgcn_global_load_lds( \
        (const __attribute__((address_space(1))) void*)(as_ + (size_t)(r_ + 32 * p_) * K + js_), \
        (__attribute__((address_space(3))) void*)(ab_ + w * 1024 + p_ * 4096), 16, 0, 0); \
      __builtin_amdgcn_global_load_lds( \
        (const __attribute__((address_space(1))) void*)(ws_ + (size_t)(r_ + 32 * p_) * K + js_), \
        (__attribute__((address_space(3))) void*)(wb_ + w * 1024 + p_ * 4096), 16, 0, 0); \
    } \
  } while (0)

  GSTAGE(0, 0);
  asm volatile("s_waitcnt vmcnt(0)" ::: "memory");
  sbar();
  #pragma unroll 1
  for (int s = 0; s < nsteps; ++s) {
    const int cur = s & 1;
    if (s + 1 < nsteps) GSTAGE(cur ^ 1, (s + 1) * 64);
    __builtin_amdgcn_sched_barrier(0);
    const char* ab = lds + cur * 16384;
    const char* wb = lds + 32768 + cur * 16384;
    __builtin_amdgcn_s_setprio(1);
    #pragma unroll
    for (int s4 = 0; s4 < 4; ++s4) {
      const int off = (s4 * 32 + lh16) ^ swz;
      bf16x8 am0 = *(const bf16x8*)(ab + (qg * 64 + l31) * 128 + off);
      bf16x8 am1 = *(const bf16x8*)(ab + (qg * 64 + 32 + l31) * 128 + off);
      bf16x8 wn0 = *(const bf16x8*)(wb + (ng * 64 + l31) * 128 + off);
      bf16x8 wn1 = *(const bf16x8*)(wb + (ng * 64 + 32 + l31) * 128 + off);
      acc00 = __builtin_amdgcn_mfma_f32_32x32x16_bf16(wn0, am0, acc00, 0, 0, 0);
      acc01 = __builtin_amdgcn_mfma_f32_32x32x16_bf16(wn1, am0, acc01, 0, 0, 0);
      acc10 = __builtin_amdgcn_mfma_f32_32x32x16_bf16(wn0, am1, acc10, 0, 0, 0);
      acc11 = __builtin_amdgcn_mfma_f32_32x32x16_bf16(wn1, am1, acc11, 0, 0, 0);
    }
    __builtin_amdgcn_s_setprio(0);
    asm volatile("s_waitcnt vmcnt(0)" ::: "memory");
    sbar();
  }
#undef GSTAGE

  // epilogue: spill to LDS (XOR-swizzled cols), then coalesced store
  float* Ls = (float*)lds;
  {
    const int m0 = qg * 64 + l31;
    const int k0 = (m0 & 7) << 2;
    #pragma unroll
    for (int r = 0; r < 16; ++r) {
      const int nd = ng * 64 + (r & 3) + 8 * (r >> 2) + 4 * lh;
      Ls[m0 * 128 + (nd ^ k0)] = acc00[r];
      Ls[m0 * 128 + ((nd + 32) ^ k0)] = acc01[r];
      Ls[(m0 + 32) * 128 + (nd ^ k0)] = acc10[r];
      Ls[(m0 + 32) * 128 + ((nd + 32) ^ k0)] = acc11[r];
    }
  }
  sbar();
  #pragma unroll
  for (int p = 0; p < 16; ++p) {
    int idx = tid + 256 * p;
    int m = idx >> 5, c4 = (idx & 31) << 2;
    float4 v = *(const float4*)&Ls[m * 128 + (c4 ^ ((m & 7) << 2))];
    int col = colBase + c4;
    float4 bv = *(const float4*)&bias[col];
    v.x += bv.x; v.y += bv.y; v.z += bv.z; v.w += bv.w;
    if (ACT) {
      v.x = lrelu_f(v.x); v.y = lrelu_f(v.y);
      v.z = lrelu_f(v.z); v.w = lrelu_f(v.w);
    }
    size_t o = (size_t)(rowBase + m) * N + col;
    if (ACCUM) {
      float4 c0 = *(const float4*)&C[o];
      v.x += c0.x; v.y += c0.y; v.z += c0.z; v.w += c0.w;
    }
    *(float4*)&C[o] = v;
    if (STOREBF) {
      ushort4 q;
      q.x = f2bf(v.x * bscale); q.y = f2bf(v.y * bscale);
      q.z = f2bf(v.z * bscale); q.w = f2bf(v.w * bscale);
      *(ushort4*)&Cb[o] = q;
    }
  }
}

// ---------------------------------------------------------------------------
// MFMA attn-logit + per-row top-6 — BARRIER-FREE, per-wave pipeline.
// 512 blocks x 256 thr (4 waves), 2 blocks/CU. XCD decode: xcd=bid&7,
// split=xcd&3 (one split = 4MB = that XCD's L2), rowTile=(xcd>>2)*64+(bid>>3).
// Per wave: 32 q-rows, A (query) fragments for ALL K=512 held in 128 VGPRs
// (loaded once, coalesced). B (neighbors) staged into WAVE-PRIVATE LDS
// (64n x 64k, double-buffered, 8 global_load_lds/lane/stage) -> counted
// s_waitcnt vmcnt(8) gives pipelining with NO s_barrier anywhere in the loop.
// Swapped-operand mfma(neighbor, query, acc): lane&31 = q-row; lane's 2x16
// acc values are neighbor scores -> in-register top-6; lh halves merged via
// shfl_xor at the end. Buffer parity = kc&1 (static); areg statically indexed.
// ---------------------------------------------------------------------------
#define T6(tv, tix, vv, cc) do { float v_ = (vv); \
  if (v_ > tv[5]) { tv[5] = v_; tix[5] = (cc); \
    if (tv[5] > tv[4]) { float t=tv[4];tv[4]=tv[5];tv[5]=t; int q=tix[4];tix[4]=tix[5];tix[5]=q; } \
    if (tv[4] > tv[3]) { float t=tv[3];tv[3]=tv[4];tv[4]=t; int q=tix[3];tix[3]=tix[4];tix[4]=q; } \
    if (tv[3] > tv[2]) { float t=tv[2];tv[2]=tv[3];tv[3]=t; int q=tix[2];tix[2]=tix[3];tix[3]=q; } \
    if (tv[2] > tv[1]) { float t=tv[1];tv[1]=tv[2];tv[2]=t; int q=tix[1];tix[1]=tix[2];tix[2]=q; } \
    if (tv[1] > tv[0]) { float t=tv[0];tv[0]=tv[1];tv[1]=t; int q=tix[0];tix[0]=tix[1];tix[1]=q; } \
  } } while (0)

__global__ __launch_bounds__(256, 2)
void attn_topk_mfma(const u16* __restrict__ EHb, const u16* __restrict__ ETb,
                    float* __restrict__ TWp, int* __restrict__ TIp) {
  __shared__ char lds[65536];            // wave w: [w*16K, w*16K+16K), 2 bufs
  const int tid = threadIdx.x;
  const int w = tid >> 6, l = tid & 63;
  const int l31 = l & 31, lh = l >> 5;

  const int bid = blockIdx.x;
  const int xcd = bid & 7;
  const int split = xcd & 3;
  const int rowBase = ((xcd >> 2) * 64 + (bid >> 3)) * 128;
  const int qrow = rowBase + w * 32 + l31;     // this lane's query row

  // ---- A (query) fragments in registers: full K=512, 32 x bf16x8 ----
  bf16x8 areg[32];
  {
    const u16* ap = EHb + (size_t)qrow * DIM + lh * 8;
    #pragma unroll
    for (int ks = 0; ks < 32; ++ks)
      areg[ks] = *(const bf16x8*)(ap + ks * 16);
  }

  char* ldsw = lds + w * 16384;

  f32x16 z;
  #pragma unroll
  for (int i = 0; i < 16; i++) z[i] = 0.f;
  f32x16 acc0 = z, acc1 = z;

  float tv[KSEL]; int tix[KSEL];
  #pragma unroll
  for (int k = 0; k < KSEL; k++) { tv[k] = -INFINITY; tix[k] = 0x7fffffff; }

  // stage 64n x 64k B tile into wave-private buf: 8 gload_lds per lane.
  // dest: instr p writes rows p*8+(l>>3), 16B chunk l&7; source pre-swizzled
  // with (row&7) XOR so fragment reads can de-swizzle (rule #21 both-sides).
#define STAGE(buf_, ct_, kc_) do { \
    char* db_ = ldsw + (buf_) * 8192; \
    const u16* bs_ = ETb + (size_t)(split * COLS_PER_SPLIT + (ct_) * 64) * DIM + (kc_) * 64; \
    _Pragma("unroll") \
    for (int p_ = 0; p_ < 8; ++p_) { \
      const int rn_ = p_ * 8 + (l >> 3); \
      const int js_ = ((l & 7) ^ (rn_ & 7)) * 8; \
      __builtin_amdgcn_global_load_lds( \
        (const __attribute__((address_space(1))) void*)(bs_ + (size_t)rn_ * DIM + js_), \
        (__attribute__((address_space(3))) void*)(db_ + p_ * 1024), 16, 0, 0); \
    } \
  } while (0)

  STAGE(0, 0, 0);
  STAGE(1, 0, 1);
  asm volatile("s_waitcnt vmcnt(8)" ::: "memory");   // A-regs + buf0 complete

  #pragma unroll 1
  for (int ct = 0; ct < 64; ++ct) {
    #pragma unroll
    for (int kc = 0; kc < 8; ++kc) {
      const char* db = ldsw + (kc & 1) * 8192;
      __builtin_amdgcn_s_setprio(1);
      #pragma unroll
      for (int s4 = 0; s4 < 4; ++s4) {
        const int c0 = ((s4 * 2 + lh) ^ (l31 & 7)) * 16;
        bf16x8 bn0 = *(const bf16x8*)(db + l31 * 128 + c0);
        const int r1 = 32 + l31;
        const int c1 = ((s4 * 2 + lh) ^ (r1 & 7)) * 16;
        bf16x8 bn1 = *(const bf16x8*)(db + r1 * 128 + c1);
        acc0 = __builtin_amdgcn_mfma_f32_32x32x16_bf16(bn0, areg[kc * 4 + s4], acc0, 0, 0, 0);
        acc1 = __builtin_amdgcn_mfma_f32_32x32x16_bf16(bn1, areg[kc * 4 + s4], acc1, 0, 0, 0);
      }
      __builtin_amdgcn_s_setprio(0);
      __builtin_amdgcn_sched_barrier(0);   // keep restage below the MFMA cluster
      if (!(ct == 63 && kc >= 6)) {
        const int nct = (kc < 6) ? ct : ct + 1;
        const int nkc = (kc + 2) & 7;
        STAGE(kc & 1, nct, nkc);
      }
      if (ct == 63 && kc >= 5) { asm volatile("s_waitcnt vmcnt(0)" ::: "memory"); }
      else                     { asm volatile("s_waitcnt vmcnt(8)" ::: "memory"); }
    }
    // end of K for this 64-col tile: per-lane top-6 insert
    {
      const int cb = split * COLS_PER_SPLIT + ct * 64 + 4 * lh;
      #pragma unroll
      for (int r = 0; r < 16; ++r) {
        const int nd = cb + (r & 3) + 8 * (r >> 2);
        T6(tv, tix, acc0[r], nd);
        T6(tv, tix, acc1[r], nd + 32);
      }
      acc0 = z; acc1 = z;
    }
  }
#undef STAGE

  // merge the two lh-half lists for this q-row (partner lane = l ^ 32)
  {
    float pv[KSEL]; int pi[KSEL];
    #pragma unroll
    for (int k = 0; k < KSEL; k++) {
      pv[k] = __shfl_xor(tv[k], 32);
      pi[k] = __shfl_xor(tix[k], 32);
    }
    #pragma unroll
    for (int k = 0; k < KSEL; k++) {
      float cv = pv[k]; int ci = pi[k];
      if ((cv > tv[5]) || (cv == tv[5] && ci < tix[5])) {
        tv[5] = cv; tix[5] = ci;
        if ((tv[5] > tv[4]) || (tv[5] == tv[4] && tix[5] < tix[4])) {
          float t = tv[4]; tv[4] = tv[5]; tv[5] = t;
          int q = tix[4]; tix[4] = tix[5]; tix[5] = q; }
        if ((tv[4] > tv[3]) || (tv[4] == tv[3] && tix[4] < tix[3])) {
          float t = tv[3]; tv[3] = tv[4]; tv[4] = t;
          int q = tix[3]; tix[3] = tix[4]; tix[4] = q; }
        if ((tv[3] > tv[2]) || (tv[3] == tv[2] && tix[3] < tix[2])) {
          float t = tv[2]; tv[2] = tv[3]; tv[3] = t;
          int q = tix[2]; tix[2] = tix[3]; tix[3] = q; }
        if ((tv[2] > tv[1]) || (tv[2] == tv[1] && tix[2] < tix[1])) {
          float t = tv[1]; tv[1] = tv[2]; tv[2] = t;
          int q = tix[1]; tix[1] = tix[2]; tix[2] = q; }
        if ((tv[1] > tv[0]) || (tv[1] == tv[0] && tix[1] < tix[0])) {
          float t = tv[0]; tv[0] = tv[1]; tv[1] = t;
          int q = tix[0]; tix[0] = tix[1]; tix[1] = q; }
      }
    }
  }
  if (lh == 0) {
    size_t o = ((size_t)split * NROWS + qrow) * KSEL;
    #pragma unroll
    for (int k = 0; k < KSEL; k++) { TWp[o + k] = tv[k]; TIp[o + k] = tix[k]; }
  }
}

// Merge NSPLIT per-split top-6 lists into global top-6 (value desc, idx asc).
__global__ __launch_bounds__(256)
void topk_merge(const float* __restrict__ TWp, const int* __restrict__ TIp,
                float* __restrict__ TW, int* __restrict__ TI) {
  int row = blockIdx.x * 256 + threadIdx.x;
  float tv[KSEL]; int tix[KSEL];
  #pragma unroll
  for (int k = 0; k < KSEL; k++) { tv[k] = -INFINITY; tix[k] = 0x7fffffff; }
  #pragma unroll
  for (int s = 0; s < NSPLIT; s++) {
    size_t o = ((size_t)s * NROWS + row) * KSEL;
    #pragma unroll
    for (int k = 0; k < KSEL; k++) {
      float cv = TWp[o + k]; int ci = TIp[o + k];
      bool better5 = (cv > tv[5]) || (cv == tv[5] && ci < tix[5]);
      if (better5) {
        tv[5] = cv; tix[5] = ci;
        if ((tv[5] > tv[4]) || (tv[5] == tv[4] && tix[5] < tix[4])) {
          float t = tv[4]; tv[4] = tv[5]; tv[5] = t;
          int ti = tix[4]; tix[4] = tix[5]; tix[5] = ti; }
        if ((tv[4] > tv[3]) || (tv[4] == tv[3] && tix[4] < tix[3])) {
          float t = tv[3]; tv[3] = tv[4]; tv[4] = t;
          int ti = tix[3]; tix[3] = tix[4]; tix[4] = ti; }
        if ((tv[3] > tv[2]) || (tv[3] == tv[2] && tix[3] < tix[2])) {
          float t = tv[2]; tv[2] = tv[3]; tv[3] = t;
          int ti = tix[2]; tix[2] = tix[3]; tix[3] = ti; }
        if ((tv[2] > tv[1]) || (tv[2] == tv[1] && tix[2] < tix[1])) {
          float t = tv[1]; tv[1] = tv[2]; tv[2] = t;
          int ti = tix[1]; tix[1] = tix[2]; tix[2] = ti; }
        if ((tv[1] > tv[0]) || (tv[1] == tv[0] && tix[1] < tix[0])) {
          float t = tv[0]; tv[0] = tv[1]; tv[1] = t;
          int ti = tix[0]; tix[0] = tix[1]; tix[1] = ti; }
      }
    }
  }
  size_t o = (size_t)row * KSEL;
  #pragma unroll
  for (int k = 0; k < KSEL; k++) { TW[o + k] = tv[k]; TI[o + k] = tix[k]; }
}

// ---------------------------------------------------------------------------
// Neighbor aggregation. One wave per row; writes bf16 s_in / b_in.
// ---------------------------------------------------------------------------
__global__ __launch_bounds__(256)
void neighbor_kernel(const float* __restrict__ EH, const float* __restrict__ ET,
                     const float* __restrict__ TW, const int* __restrict__ TI,
                     u16* __restrict__ SINb, u16* __restrict__ BINb) {
  const int lane = threadIdx.x & 63;
  const int row = blockIdx.x * 4 + (threadIdx.x >> 6);
  const float* eh = EH + (size_t)row * DIM;
  float ehv[8];
  #pragma unroll
  for (int u = 0; u < 8; u++) ehv[u] = eh[u * 64 + lane];
  float tw[KSEL]; int ti[KSEL];
  #pragma unroll
  for (int k = 0; k < KSEL; k++) {
    tw[k] = TW[(size_t)row * KSEL + k];
    ti[k] = TI[(size_t)row * KSEL + k];
  }
  float m = tw[0];
  #pragma unroll
  for (int k = 1; k < KSEL; k++) m = fmaxf(m, tw[k]);
  float p[KSEL], ps = 0.f;
  #pragma unroll
  for (int k = 0; k < KSEL; k++) { p[k] = expf(tw[k] - m); ps += p[k]; }
  float inv = 1.f / ps;
  #pragma unroll
  for (int k = 0; k < KSEL; k++) p[k] *= inv;

  float nb[KSEL][8];
  float kaw[KSEL];
  #pragma unroll
  for (int k = 0; k < KSEL; k++) {
    const float* et = ET + (size_t)ti[k] * DIM;
    float snb = 0.f, sg = 0.f;
    #pragma unroll
    for (int u = 0; u < 8; u++) {
      float nbv = et[u * 64 + lane];
      nb[k][u] = nbv;
      float ehr = p[k] * nbv + (1.f - p[k]) * ehv[u];
      float g = tanhf(ehv[u] + ehr);
      snb += nbv; sg += g;
    }
    #pragma unroll
    for (int off = 32; off > 0; off >>= 1) {
      snb += __shfl_xor(snb, off);
      sg  += __shfl_xor(sg, off);
    }
    kaw[k] = snb * sg;
  }
  float km = kaw[0];
  #pragma unroll
  for (int k = 1; k < KSEL; k++) km = fmaxf(km, kaw[k]);
  float kp[KSEL], ks = 0.f;
  #pragma unroll
  for (int k = 0; k < KSEL; k++) { kp[k] = expf(kaw[k] - km); ks += kp[k]; }
  float kinv = 1.f / ks;
  #pragma unroll
  for (int k = 0; k < KSEL; k++) kp[k] *= kinv;

  #pragma unroll
  for (int u = 0; u < 8; u++) {
    float enh = 0.f;
    #pragma unroll
    for (int k = 0; k < KSEL; k++) enh += kp[k] * nb[k][u];
    size_t o = (size_t)row * DIM + u * 64 + lane;
    SINb[o] = f2bf(ehv[u] + enh);
    BINb[o] = f2bf(ehv[u] * enh);
  }
}

__global__ __launch_bounds__(256)
void att2_kernel(const float* __restrict__ HID, const float* __restrict__ w2,
                 const float* __restrict__ b2, float* __restrict__ ASC) {
  const int lane = threadIdx.x & 63;
  const int row = blockIdx.x * 4 + (threadIdx.x >> 6);
  float4 hv = ((const float4*)(HID + (size_t)row * 256))[lane];
  float4 wv = ((const float4*)w2)[lane];
  float s = hv.x * wv.x + hv.y * wv.y + hv.z * wv.z + hv.w * wv.w;
  #pragma unroll
  for (int off = 32; off > 0; off >>= 1) s += __shfl_xor(s, off);
  if (lane == 0) ASC[row] = s + b2[0];
}

__global__ __launch_bounds__(1024)
void areduce(const float* __restrict__ ASC, float* __restrict__ stats) {
  __shared__ float sm[1024];
  int t = threadIdx.x;
  float m = -INFINITY;
  for (int i = t; i < NROWS; i += 1024) m = fmaxf(m, ASC[i]);
  sm[t] = m; __syncthreads();
  for (int s = 512; s > 0; s >>= 1) {
    if (t < s) sm[t] = fmaxf(sm[t], sm[t + s]);
    __syncthreads();
  }
  float mx = sm[0]; __syncthreads();
  float sum = 0.f;
  for (int i = t; i < NROWS; i += 1024) sum += expf(ASC[i] - mx);
  sm[t] = sum; __syncthreads();
  for (int s = 512; s > 0; s >>= 1) {
    if (t < s) sm[t] += sm[t + s];
    __syncthreads();
  }
  if (t == 0) { stats[0] = mx; stats[1] = sm[0]; }
}

__global__ __launch_bounds__(256)
void pooled_partial(const float* __restrict__ EMB, const float* __restrict__ ASC,
                    const float* __restrict__ stats, float* __restrict__ part) {
  int col = blockIdx.x * 64 + (threadIdx.x & 63);
  int sub = threadIdx.x >> 6;
  float mx = stats[0];
  int rEnd = blockIdx.y * 512 + 512;
  float s = 0.f;
  for (int r = blockIdx.y * 512 + sub; r < rEnd; r += 4)
    s += expf(ASC[r] - mx) * EMB[(size_t)r * DIM + col];
  __shared__ float sh[4][64];
  sh[sub][threadIdx.x & 63] = s;
  __syncthreads();
  if (threadIdx.x < 64) {
    float tot = sh[0][threadIdx.x] + sh[1][threadIdx.x] +
                sh[2][threadIdx.x] + sh[3][threadIdx.x];
    part[(size_t)blockIdx.y * DIM + col] = tot;
  }
}

__global__ __launch_bounds__(512)
void final_kernel(const float* __restrict__ part, const float* __restrict__ stats,
                  const float* __restrict__ ln_g, const float* __restrict__ ln_b,
                  const float* __restrict__ fc_w, const float* __restrict__ fc_b,
                  float* __restrict__ out) {
  __shared__ float sh[512];
  int t = threadIdx.x;
  float s = 0.f;
  for (int j = 0; j < 32; j++) s += part[j * DIM + t];
  float pooled = s / stats[1];
  sh[t] = pooled; __syncthreads();
  for (int off = 256; off > 0; off >>= 1) {
    if (t < off) sh[t] += sh[t + off];
    __syncthreads();
  }
  float mu = sh[0] * (1.f / DIM); __syncthreads();
  float dv = pooled - mu;
  sh[t] = dv * dv; __syncthreads();
  for (int off = 256; off > 0; off >>= 1) {
    if (t < off) sh[t] += sh[t + off];
    __syncthreads();
  }
  float var = sh[0] * (1.f / DIM); __syncthreads();
  float normed = dv * rsqrtf(var + 1e-5f) * ln_g[t] + ln_b[t];
  sh[t] = normed * fc_w[t * 2 + 0]; __syncthreads();
  for (int off = 256; off > 0; off >>= 1) {
    if (t < off) sh[t] += sh[t + off];
    __syncthreads();
  }
  float l0 = sh[0] + fc_b[0]; __syncthreads();
  sh[t] = normed * fc_w[t * 2 + 1]; __syncthreads();
  for (int off = 256; off > 0; off >>= 1) {
    if (t < off) sh[t] += sh[t + off];
    __syncthreads();
  }
  float l1 = sh[0] + fc_b[1];
  if (t == 0) {
    float mm = fmaxf(l0, l1);
    float e0 = expf(l0 - mm), e1 = expf(l1 - mm);
    float si = 1.f / (e0 + e1);
    out[0] = l0; out[1] = l1; out[2] = e0 * si; out[3] = e1 * si;
  }
}

// ---------------------------------------------------------------------------
extern "C" void kernel_launch(void* const* d_in, const int* in_sizes, int n_in,
                              void* d_out, int out_size, void* d_ws, size_t ws_size,
                              hipStream_t stream) {
  (void)in_sizes; (void)n_in; (void)out_size; (void)ws_size;
  const float* x      = (const float*)d_in[0];
  const float* fc1_w  = (const float*)d_in[1];
  const float* fc1_b  = (const float*)d_in[2];
  const float* wh_w   = (const float*)d_in[3];
  const float* wh_b   = (const float*)d_in[4];
  const float* wt_w   = (const float*)d_in[5];
  const float* wt_b   = (const float*)d_in[6];
  const float* lin1_w = (const float*)d_in[7];
  const float* lin1_b = (const float*)d_in[8];
  const float* lin2_w = (const float*)d_in[9];
  const float* lin2_b = (const float*)d_in[10];
  const float* att1_w = (const float*)d_in[11];
  const float* att1_b = (const float*)d_in[12];
  const float* att2_w = (const float*)d_in[13];
  const float* att2_b = (const float*)d_in[14];
  const float* ln_g   = (const float*)d_in[15];
  const float* ln_b   = (const float*)d_in[16];
  const float* fc_w   = (const float*)d_in[17];
  const float* fc_b   = (const float*)d_in[18];
  float* out = (float*)d_out;

  char* ws = (char*)d_ws;
  float* B0   = (float*)(ws);                       // h0 -> HID
  float* B1   = (float*)(ws + 33554432);            // [xb] -> e_h
  float* B2   = (float*)(ws + 67108864);            // e_t -> emb
  float* TWp  = (float*)(ws + 100663296);
  int*   TIp  = (int*)  (ws + 100663296 + 1572864);
  float* TW   = (float*)(ws + 100663296 + 3145728);
  int*   TI   = (int*)  (ws + 100663296 + 3145728 + 393216);
  float* part = (float*)(ws + 100663296 + 3145728 + 786432);
  float* mean = (float*)(ws + 100663296 + 3145728 + 786432 + 65536);
  float* ascr = (float*)(ws + 100663296 + 3145728 + 786432 + 65536 + 2048);
  float* stats= (float*)(ws + 100663296 + 3145728 + 786432 + 65536 + 2048 + 65536);
  u16*   hb   = (u16*)(ws + 104732672);             // -> embb
  u16*   EHb  = (u16*)(ws + 104732672 + 16777216);  // -> sinb
  u16*   ETb  = (u16*)(ws + 104732672 + 33554432);  // -> binb
  u16*   WT   = (u16*)(ws + 104732672 + 50331648);  // transposed bf16 weights
  u16* fc1t = WT;
  u16* wht  = fc1t + 196608;
  u16* wtt  = wht + 262144;
  u16* lin1t= wtt + 262144;
  u16* lin2t= lin1t + 262144;
  u16* att1t= lin2t + 262144;
  u16* xb   = (u16*)B1;      // temp in B1 region, dead before e_h written
  u16* sinb = EHb;           // reuse after attn
  u16* binb = ETb;
  u16* embb = hb;

  // 0. input + weight conversions (bf16, weights transposed to [N][K])
  convx<<<3072, 256, 0, stream>>>(x, xb);
  wconv<<<768, 256, 0, stream>>>(fc1_w, fc1t, 384, 512);
  wconv<<<1024, 256, 0, stream>>>(wh_w, wht, 512, 512);
  wconv<<<1024, 256, 0, stream>>>(wt_w, wtt, 512, 512);
  wconv<<<1024, 256, 0, stream>>>(lin1_w, lin1t, 512, 512);
  wconv<<<1024, 256, 0, stream>>>(lin2_w, lin2t, 512, 512);
  wconv<<<512, 256, 0, stream>>>(att1_w, att1t, 512, 256);
  // 1. h0 = lrelu(x @ fc1_w + b)
  gemm_bf16<1,0,0><<<dim3(4,128), 256, 0, stream>>>(xb, fc1t, fc1_b, B0, nullptr, 1.f, 384, 512);
  // 2-4. column mean; hb = bf16((h0+mean)*0.5)
  colsum_partial<<<dim3(8,32), 256, 0, stream>>>(B0, part);
  finalize_mean<<<1, 512, 0, stream>>>(part, mean);
  h_fix_bf<<<4096, 256, 0, stream>>>(B0, mean, hb);
  // 5-6. e_h (f32 + bf16*SCALE), e_t (f32 + bf16)
  gemm_bf16<0,0,1><<<dim3(4,128), 256, 0, stream>>>(hb, wht, wh_b, B1, EHb, ATT_SCALE, 512, 512);
  gemm_bf16<0,0,1><<<dim3(4,128), 256, 0, stream>>>(hb, wtt, wt_b, B2, ETb, 1.f, 512, 512);
  // 7. fused MFMA attn-logit + top-6 per split (barrier-free), then merge
  attn_topk_mfma<<<512, 256, 0, stream>>>(EHb, ETb, TWp, TIp);
  topk_merge<<<64, 256, 0, stream>>>(TWp, TIp, TW, TI);
  // 8. neighbor aggregation -> bf16 s_in / b_in
  neighbor_kernel<<<4096, 256, 0, stream>>>(B1, B2, TW, TI, sinb, binb);
  // 9-10. emb = lrelu(s_in@lin1+b) + lrelu(b_in@lin2+b)  (f32 in B2 + bf16)
  gemm_bf16<1,0,0><<<dim3(4,128), 256, 0, stream>>>(sinb, lin1t, lin1_b, B2, nullptr, 1.f, 512, 512);
  gemm_bf16<1,1,1><<<dim3(4,128), 256, 0, stream>>>(binb, lin2t, lin2_b, B2, embb, 1.f, 512, 512);
  // 11. hidden = lrelu(emb@att1+b) -> B0 f32
  gemm_bf16<1,0,0><<<dim3(2,128), 256, 0, stream>>>(embb, att1t, att1_b, B0, nullptr, 1.f, 512, 256);
  // 12-15. readout
  att2_kernel<<<4096, 256, 0, stream>>>(B0, att2_w, att2_b, ascr);
  areduce<<<1, 1024, 0, stream>>>(ascr, stats);
  pooled_partial<<<dim3(8,32), 256, 0, stream>>>(B2, ascr, stats, part);
  final_kernel<<<1, 512, 0, stream>>>(part, stats, ln_g, ln_b, fc_w, fc_b, out);
}

// Round 8
// 598.949 us; speedup vs baseline: 1.4234x; 1.1137x over previous
//
#include <hip/hip_runtime.h>
#include <math.h>

#define NROWS 16384
#define DIN   384
#define DIM   512
#define KSEL  6
#define NSPLIT 4
#define COLS_PER_SPLIT (NROWS / NSPLIT)   // 4096
#define ATT_SCALE 0.044194173824159216f   // 512^-0.5

typedef unsigned short u16;
typedef __attribute__((ext_vector_type(8))) short bf16x8;
typedef __attribute__((ext_vector_type(16))) float f32x16;

static __device__ __forceinline__ float lrelu_f(float v) {
  return v > 0.f ? v : 0.01f * v;
}

static __device__ __forceinline__ u16 f2bf(float f) {  // RNE f32->bf16
  unsigned u = __float_as_uint(f);
  unsigned r = (u + 0x7FFFu + ((u >> 16) & 1u)) >> 16;
  return (u16)r;
}

static __device__ __forceinline__ void sbar() {
  asm volatile("" ::: "memory");
  __builtin_amdgcn_s_barrier();
  asm volatile("" ::: "memory");
}

// ---------------------------------------------------------------------------
// small elementwise kernels
// ---------------------------------------------------------------------------
__global__ __launch_bounds__(256)
void convx(const float* __restrict__ X, u16* __restrict__ Xb) {
  int i = blockIdx.x * 256 + threadIdx.x;           // 8-elem chunk
  const float4* p = (const float4*)X + (size_t)i * 2;
  float4 a = p[0], b = p[1];
  uint4 o;
  o.x = f2bf(a.x) | ((unsigned)f2bf(a.y) << 16);
  o.y = f2bf(a.z) | ((unsigned)f2bf(a.w) << 16);
  o.z = f2bf(b.x) | ((unsigned)f2bf(b.y) << 16);
  o.w = f2bf(b.z) | ((unsigned)f2bf(b.w) << 16);
  ((uint4*)Xb)[i] = o;
}

__global__ __launch_bounds__(256)
void wconv(const float* __restrict__ W, u16* __restrict__ Wt, int K, int N) {
  int t = blockIdx.x * 256 + threadIdx.x;
  if (t >= K * N) return;
  int k = t / N, n = t - k * N;
  Wt[(size_t)n * K + k] = f2bf(W[t]);
}

__global__ __launch_bounds__(256)
void colsum_partial(const float* __restrict__ H, float* __restrict__ part) {
  int col = blockIdx.x * 64 + (threadIdx.x & 63);
  int sub = threadIdx.x >> 6;
  int rEnd = blockIdx.y * 512 + 512;
  float s = 0.f;
  for (int r = blockIdx.y * 512 + sub; r < rEnd; r += 4)
    s += H[(size_t)r * DIM + col];
  __shared__ float sh[4][64];
  sh[sub][threadIdx.x & 63] = s;
  __syncthreads();
  if (threadIdx.x < 64) {
    float tot = sh[0][threadIdx.x] + sh[1][threadIdx.x] +
                sh[2][threadIdx.x] + sh[3][threadIdx.x];
    part[(size_t)blockIdx.y * DIM + col] = tot;
  }
}

__global__ void finalize_mean(const float* __restrict__ part,
                              float* __restrict__ mean) {
  int c = threadIdx.x;
  float s = 0.f;
  for (int j = 0; j < 32; j++) s += part[j * DIM + c];
  mean[c] = s * (1.0f / NROWS);
}

// h = (h0 + mean)*0.5, bf16 output only
__global__ __launch_bounds__(256)
void h_fix_bf(const float* __restrict__ H0, const float* __restrict__ mean,
              u16* __restrict__ Hb) {
  int idx = blockIdx.x * 256 + threadIdx.x;         // 8-elem chunk
  int c = (idx * 8) & (DIM - 1);
  const float4* p = (const float4*)H0 + (size_t)idx * 2;
  float4 a = p[0], b = p[1];
  float4 m0 = *(const float4*)(mean + c);
  float4 m1 = *(const float4*)(mean + c + 4);
  a.x = (a.x + m0.x) * 0.5f; a.y = (a.y + m0.y) * 0.5f;
  a.z = (a.z + m0.z) * 0.5f; a.w = (a.w + m0.w) * 0.5f;
  b.x = (b.x + m1.x) * 0.5f; b.y = (b.y + m1.y) * 0.5f;
  b.z = (b.z + m1.z) * 0.5f; b.w = (b.w + m1.w) * 0.5f;
  uint4 o;
  o.x = f2bf(a.x) | ((unsigned)f2bf(a.y) << 16);
  o.y = f2bf(a.z) | ((unsigned)f2bf(a.w) << 16);
  o.z = f2bf(b.x) | ((unsigned)f2bf(b.y) << 16);
  o.w = f2bf(b.z) | ((unsigned)f2bf(b.w) << 16);
  ((uint4*)Hb)[idx] = o;
}

// ---------------------------------------------------------------------------
// bf16 MFMA GEMM (unchanged): C = act(A@Wt^T + bias), opt +=, opt bf16 store.
// ---------------------------------------------------------------------------
template<int ACT, int ACCUM, int STOREBF>
__global__ __launch_bounds__(256, 2)
void gemm_bf16(const u16* __restrict__ A, const u16* __restrict__ Wt,
               const float* __restrict__ bias, float* __restrict__ C,
               u16* __restrict__ Cb, float bscale, int K, int N) {
  __shared__ char lds[65536];   // A dbuf [0,32K), W dbuf [32K,64K)
  const int tid = threadIdx.x;
  const int w = tid >> 6, l = tid & 63;
  const int l31 = l & 31, lh = l >> 5, lh16 = lh << 4;
  const int qg = w & 1, ng = w >> 1;
  const int swz = (l31 & 7) << 4;
  const int rowBase = blockIdx.y * 128;
  const int colBase = blockIdx.x * 128;
  const int nsteps = K >> 6;

  f32x16 z;
  #pragma unroll
  for (int i = 0; i < 16; i++) z[i] = 0.f;
  f32x16 acc00 = z, acc01 = z, acc10 = z, acc11 = z;

#define GSTAGE(buf_, kc_) do { \
    const int r_ = tid >> 3, j_ = tid & 7; \
    const int js_ = ((j_ ^ (r_ & 7)) << 3); \
    const u16* as_ = A + (size_t)rowBase * K + (kc_); \
    const u16* ws_ = Wt + (size_t)colBase * K + (kc_); \
    char* ab_ = lds + (buf_) * 16384; \
    char* wb_ = lds + 32768 + (buf_) * 16384; \
    _Pragma("unroll") \
    for (int p_ = 0; p_ < 4; ++p_) { \
      __builtin_amdgcn_global_load_lds( \
        (const __attribute__((address_space(1))) void*)(as_ + (size_t)(r_ + 32 * p_) * K + js_), \
        (__attribute__((address_space(3))) void*)(ab_ + w * 1024 + p_ * 4096), 16, 0, 0); \
      __builtin_amdgcn_global_load_lds( \
        (const __attribute__((address_space(1))) void*)(ws_ + (size_t)(r_ + 32 * p_) * K + js_), \
        (__attribute__((address_space(3))) void*)(wb_ + w * 1024 + p_ * 4096), 16, 0, 0); \
    } \
  } while (0)

  GSTAGE(0, 0);
  asm volatile("s_waitcnt vmcnt(0)" ::: "memory");
  sbar();
  #pragma unroll 1
  for (int s = 0; s < nsteps; ++s) {
    const int cur = s & 1;
    if (s + 1 < nsteps) GSTAGE(cur ^ 1, (s + 1) * 64);
    __builtin_amdgcn_sched_barrier(0);
    const char* ab = lds + cur * 16384;
    const char* wb = lds + 32768 + cur * 16384;
    __builtin_amdgcn_s_setprio(1);
    #pragma unroll
    for (int s4 = 0; s4 < 4; ++s4) {
      const int off = (s4 * 32 + lh16) ^ swz;
      bf16x8 am0 = *(const bf16x8*)(ab + (qg * 64 + l31) * 128 + off);
      bf16x8 am1 = *(const bf16x8*)(ab + (qg * 64 + 32 + l31) * 128 + off);
      bf16x8 wn0 = *(const bf16x8*)(wb + (ng * 64 + l31) * 128 + off);
      bf16x8 wn1 = *(const bf16x8*)(wb + (ng * 64 + 32 + l31) * 128 + off);
      acc00 = __builtin_amdgcn_mfma_f32_32x32x16_bf16(wn0, am0, acc00, 0, 0, 0);
      acc01 = __builtin_amdgcn_mfma_f32_32x32x16_bf16(wn1, am0, acc01, 0, 0, 0);
      acc10 = __builtin_amdgcn_mfma_f32_32x32x16_bf16(wn0, am1, acc10, 0, 0, 0);
      acc11 = __builtin_amdgcn_mfma_f32_32x32x16_bf16(wn1, am1, acc11, 0, 0, 0);
    }
    __builtin_amdgcn_s_setprio(0);
    asm volatile("s_waitcnt vmcnt(0)" ::: "memory");
    sbar();
  }
#undef GSTAGE

  // epilogue: spill to LDS (XOR-swizzled cols), then coalesced store
  float* Ls = (float*)lds;
  {
    const int m0 = qg * 64 + l31;
    const int k0 = (m0 & 7) << 2;
    #pragma unroll
    for (int r = 0; r < 16; ++r) {
      const int nd = ng * 64 + (r & 3) + 8 * (r >> 2) + 4 * lh;
      Ls[m0 * 128 + (nd ^ k0)] = acc00[r];
      Ls[m0 * 128 + ((nd + 32) ^ k0)] = acc01[r];
      Ls[(m0 + 32) * 128 + (nd ^ k0)] = acc10[r];
      Ls[(m0 + 32) * 128 + ((nd + 32) ^ k0)] = acc11[r];
    }
  }
  sbar();
  #pragma unroll
  for (int p = 0; p < 16; ++p) {
    int idx = tid + 256 * p;
    int m = idx >> 5, c4 = (idx & 31) << 2;
    float4 v = *(const float4*)&Ls[m * 128 + (c4 ^ ((m & 7) << 2))];
    int col = colBase + c4;
    float4 bv = *(const float4*)&bias[col];
    v.x += bv.x; v.y += bv.y; v.z += bv.z; v.w += bv.w;
    if (ACT) {
      v.x = lrelu_f(v.x); v.y = lrelu_f(v.y);
      v.z = lrelu_f(v.z); v.w = lrelu_f(v.w);
    }
    size_t o = (size_t)(rowBase + m) * N + col;
    if (ACCUM) {
      float4 c0 = *(const float4*)&C[o];
      v.x += c0.x; v.y += c0.y; v.z += c0.z; v.w += c0.w;
    }
    *(float4*)&C[o] = v;
    if (STOREBF) {
      ushort4 q;
      q.x = f2bf(v.x * bscale); q.y = f2bf(v.y * bscale);
      q.z = f2bf(v.z * bscale); q.w = f2bf(v.w * bscale);
      *(ushort4*)&Cb[o] = q;
    }
  }
}

// ---------------------------------------------------------------------------
// MFMA attn-logit + per-row top-6 — SHARED-B triple-buffer, counted vmcnt.
// 512 blocks x 256 thr (4 waves), 2 blocks/CU, 24 KB LDS. XCD decode (R5,
// FETCH-verified): xcd=bid&7, split=xcd&3 (4MB B set = XCD L2),
// rowBase=((xcd>>2)*64+(bid>>3))*128.
// Per wave: 32 q-rows; A (query) for full K=512 in 128 regs (loaded once).
// B: ONE 64n x 64k tile (8 KB) staged per block per phase (2 gload_lds per
// thread), 3 shared buffers. Phase = {sbar; 8 ds_read + 8 MFMA (setprio);
// [T6 at kc==7]; STAGE(p+2); vmcnt(2)}. Triple buffer makes the single
// barrier hazard-safe; loads get ~1.5 phases to land (never drained to 0
// except the tail). Swapped-operand mfma(neighbor, query): lane&31 = q-row ->
// in-register top-6; lh halves merged via shfl_xor at the end.
// ---------------------------------------------------------------------------
#define T6(tv, tix, vv, cc) do { float v_ = (vv); \
  if (v_ > tv[5]) { tv[5] = v_; tix[5] = (cc); \
    if (tv[5] > tv[4]) { float t=tv[4];tv[4]=tv[5];tv[5]=t; int q=tix[4];tix[4]=tix[5];tix[5]=q; } \
    if (tv[4] > tv[3]) { float t=tv[3];tv[3]=tv[4];tv[4]=t; int q=tix[3];tix[3]=tix[4];tix[4]=q; } \
    if (tv[3] > tv[2]) { float t=tv[2];tv[2]=tv[3];tv[3]=t; int q=tix[2];tix[2]=tix[3];tix[3]=q; } \
    if (tv[2] > tv[1]) { float t=tv[1];tv[1]=tv[2];tv[2]=t; int q=tix[1];tix[1]=tix[2];tix[2]=q; } \
    if (tv[1] > tv[0]) { float t=tv[0];tv[0]=tv[1];tv[1]=t; int q=tix[0];tix[0]=tix[1];tix[1]=q; } \
  } } while (0)

__global__ __launch_bounds__(256, 2)
void attn_topk_mfma(const u16* __restrict__ EHb, const u16* __restrict__ ETb,
                    float* __restrict__ TWp, int* __restrict__ TIp) {
  __shared__ char lds[24576];            // 3 shared B buffers x 8 KB
  const int tid = threadIdx.x;
  const int w = tid >> 6, l = tid & 63;
  const int l31 = l & 31, lh = l >> 5;

  const int bid = blockIdx.x;
  const int xcd = bid & 7;
  const int split = xcd & 3;
  const int rowBase = ((xcd >> 2) * 64 + (bid >> 3)) * 128;
  const int qrow = rowBase + w * 32 + l31;     // this lane's query row

  // ---- A (query) fragments in registers: full K=512, 32 x bf16x8 ----
  bf16x8 areg[32];
  {
    const u16* ap = EHb + (size_t)qrow * DIM + lh * 8;
    #pragma unroll
    for (int ks = 0; ks < 32; ++ks)
      areg[ks] = *(const bf16x8*)(ap + ks * 16);
  }

  f32x16 z;
  #pragma unroll
  for (int i = 0; i < 16; i++) z[i] = 0.f;
  f32x16 acc0 = z, acc1 = z;

  float tv[KSEL]; int tix[KSEL];
  #pragma unroll
  for (int k = 0; k < KSEL; k++) { tv[k] = -INFINITY; tix[k] = 0x7fffffff; }

  // Cooperative stage of one 64n x 64k tile (8 KB): 2 gload_lds per thread.
  // chunk c = tid + 256*p: row c>>3, granule c&7; source granule XOR (row&7)
  // (rule #21: linear dest + pre-swizzled source; reads de-swizzle).
#define STAGE(bufi_, ph_) do { \
    const int ct_ = (ph_) >> 3, kc_ = (ph_) & 7; \
    char* db_ = lds + (bufi_) * 8192; \
    const u16* bs_ = ETb + (size_t)(split * COLS_PER_SPLIT + ct_ * 64) * DIM + kc_ * 64; \
    _Pragma("unroll") \
    for (int p_ = 0; p_ < 2; ++p_) { \
      const int c_ = tid + 256 * p_; \
      const int rn_ = c_ >> 3; \
      const int js_ = (((c_ & 7) ^ (rn_ & 7)) << 3); \
      __builtin_amdgcn_global_load_lds( \
        (const __attribute__((address_space(1))) void*)(bs_ + (size_t)rn_ * DIM + js_), \
        (__attribute__((address_space(3))) void*)(db_ + w * 1024 + p_ * 4096), 16, 0, 0); \
    } \
  } while (0)

  int bufr = 0;                    // buffer holding the current phase's tile
  STAGE(0, 0);
  STAGE(1, 1);
  asm volatile("s_waitcnt vmcnt(2)" ::: "memory");   // stage(0) landed

  #pragma unroll 1
  for (int ct = 0; ct < 64; ++ct) {
    #pragma unroll
    for (int kc = 0; kc < 8; ++kc) {
      sbar();                                  // all waves: stage(p) landed,
                                               // phase p-1 reads done
      const char* db = lds + bufr * 8192;
      __builtin_amdgcn_s_setprio(1);
      #pragma unroll
      for (int s4 = 0; s4 < 4; ++s4) {
        const int c0 = ((s4 * 2 + lh) ^ (l31 & 7)) * 16;
        bf16x8 bn0 = *(const bf16x8*)(db + l31 * 128 + c0);
        const int r1 = 32 + l31;
        const int c1 = ((s4 * 2 + lh) ^ (r1 & 7)) * 16;
        bf16x8 bn1 = *(const bf16x8*)(db + r1 * 128 + c1);
        acc0 = __builtin_amdgcn_mfma_f32_32x32x16_bf16(bn0, areg[kc * 4 + s4], acc0, 0, 0, 0);
        acc1 = __builtin_amdgcn_mfma_f32_32x32x16_bf16(bn1, areg[kc * 4 + s4], acc1, 0, 0, 0);
      }
      __builtin_amdgcn_s_setprio(0);
      if (kc == 7) {                           // end of K for this 64-col tile
        const int cb = split * COLS_PER_SPLIT + ct * 64 + 4 * lh;
        #pragma unroll
        for (int r = 0; r < 16; ++r) {
          const int nd = cb + (r & 3) + 8 * (r >> 2);
          T6(tv, tix, acc0[r], nd);
          T6(tv, tix, acc1[r], nd + 32);
        }
        acc0 = z; acc1 = z;
      }
      __builtin_amdgcn_sched_barrier(0);       // keep stage below MFMA cluster
      {
        const int p = ct * 8 + kc;
        if (p + 2 < 512) {
          const int bs = (bufr >= 1) ? bufr - 1 : bufr + 2;   // (bufr+2)%3
          STAGE(bs, p + 2);
        }
        if (p < 510) { asm volatile("s_waitcnt vmcnt(2)" ::: "memory"); }
        else         { asm volatile("s_waitcnt vmcnt(0)" ::: "memory"); }
      }
      bufr = (bufr == 2) ? 0 : bufr + 1;
    }
  }
#undef STAGE

  // merge the two lh-half lists for this q-row (partner lane = l ^ 32)
  {
    float pv[KSEL]; int pi[KSEL];
    #pragma unroll
    for (int k = 0; k < KSEL; k++) {
      pv[k] = __shfl_xor(tv[k], 32);
      pi[k] = __shfl_xor(tix[k], 32);
    }
    #pragma unroll
    for (int k = 0; k < KSEL; k++) {
      float cv = pv[k]; int ci = pi[k];
      if ((cv > tv[5]) || (cv == tv[5] && ci < tix[5])) {
        tv[5] = cv; tix[5] = ci;
        if ((tv[5] > tv[4]) || (tv[5] == tv[4] && tix[5] < tix[4])) {
          float t = tv[4]; tv[4] = tv[5]; tv[5] = t;
          int q = tix[4]; tix[4] = tix[5]; tix[5] = q; }
        if ((tv[4] > tv[3]) || (tv[4] == tv[3] && tix[4] < tix[3])) {
          float t = tv[3]; tv[3] = tv[4]; tv[4] = t;
          int q = tix[3]; tix[3] = tix[4]; tix[4] = q; }
        if ((tv[3] > tv[2]) || (tv[3] == tv[2] && tix[3] < tix[2])) {
          float t = tv[2]; tv[2] = tv[3]; tv[3] = t;
          int q = tix[2]; tix[2] = tix[3]; tix[3] = q; }
        if ((tv[2] > tv[1]) || (tv[2] == tv[1] && tix[2] < tix[1])) {
          float t = tv[1]; tv[1] = tv[2]; tv[2] = t;
          int q = tix[1]; tix[1] = tix[2]; tix[2] = q; }
        if ((tv[1] > tv[0]) || (tv[1] == tv[0] && tix[1] < tix[0])) {
          float t = tv[0]; tv[0] = tv[1]; tv[1] = t;
          int q = tix[0]; tix[0] = tix[1]; tix[1] = q; }
      }
    }
  }
  if (lh == 0) {
    size_t o = ((size_t)split * NROWS + qrow) * KSEL;
    #pragma unroll
    for (int k = 0; k < KSEL; k++) { TWp[o + k] = tv[k]; TIp[o + k] = tix[k]; }
  }
}

// Merge NSPLIT per-split top-6 lists into global top-6 (value desc, idx asc).
__global__ __launch_bounds__(256)
void topk_merge(const float* __restrict__ TWp, const int* __restrict__ TIp,
                float* __restrict__ TW, int* __restrict__ TI) {
  int row = blockIdx.x * 256 + threadIdx.x;
  float tv[KSEL]; int tix[KSEL];
  #pragma unroll
  for (int k = 0; k < KSEL; k++) { tv[k] = -INFINITY; tix[k] = 0x7fffffff; }
  #pragma unroll
  for (int s = 0; s < NSPLIT; s++) {
    size_t o = ((size_t)s * NROWS + row) * KSEL;
    #pragma unroll
    for (int k = 0; k < KSEL; k++) {
      float cv = TWp[o + k]; int ci = TIp[o + k];
      bool better5 = (cv > tv[5]) || (cv == tv[5] && ci < tix[5]);
      if (better5) {
        tv[5] = cv; tix[5] = ci;
        if ((tv[5] > tv[4]) || (tv[5] == tv[4] && tix[5] < tix[4])) {
          float t = tv[4]; tv[4] = tv[5]; tv[5] = t;
          int ti = tix[4]; tix[4] = tix[5]; tix[5] = ti; }
        if ((tv[4] > tv[3]) || (tv[4] == tv[3] && tix[4] < tix[3])) {
          float t = tv[3]; tv[3] = tv[4]; tv[4] = t;
          int ti = tix[3]; tix[3] = tix[4]; tix[4] = ti; }
        if ((tv[3] > tv[2]) || (tv[3] == tv[2] && tix[3] < tix[2])) {
          float t = tv[2]; tv[2] = tv[3]; tv[3] = t;
          int ti = tix[2]; tix[2] = tix[3]; tix[3] = ti; }
        if ((tv[2] > tv[1]) || (tv[2] == tv[1] && tix[2] < tix[1])) {
          float t = tv[1]; tv[1] = tv[2]; tv[2] = t;
          int ti = tix[1]; tix[1] = tix[2]; tix[2] = ti; }
        if ((tv[1] > tv[0]) || (tv[1] == tv[0] && tix[1] < tix[0])) {
          float t = tv[0]; tv[0] = tv[1]; tv[1] = t;
          int ti = tix[0]; tix[0] = tix[1]; tix[1] = ti; }
      }
    }
  }
  size_t o = (size_t)row * KSEL;
  #pragma unroll
  for (int k = 0; k < KSEL; k++) { TW[o + k] = tv[k]; TI[o + k] = tix[k]; }
}

// ---------------------------------------------------------------------------
// Neighbor aggregation. One wave per row; writes bf16 s_in / b_in.
// ---------------------------------------------------------------------------
__global__ __launch_bounds__(256)
void neighbor_kernel(const float* __restrict__ EH, const float* __restrict__ ET,
                     const float* __restrict__ TW, const int* __restrict__ TI,
                     u16* __restrict__ SINb, u16* __restrict__ BINb) {
  const int lane = threadIdx.x & 63;
  const int row = blockIdx.x * 4 + (threadIdx.x >> 6);
  const float* eh = EH + (size_t)row * DIM;
  float ehv[8];
  #pragma unroll
  for (int u = 0; u < 8; u++) ehv[u] = eh[u * 64 + lane];
  float tw[KSEL]; int ti[KSEL];
  #pragma unroll
  for (int k = 0; k < KSEL; k++) {
    tw[k] = TW[(size_t)row * KSEL + k];
    ti[k] = TI[(size_t)row * KSEL + k];
  }
  float m = tw[0];
  #pragma unroll
  for (int k = 1; k < KSEL; k++) m = fmaxf(m, tw[k]);
  float p[KSEL], ps = 0.f;
  #pragma unroll
  for (int k = 0; k < KSEL; k++) { p[k] = expf(tw[k] - m); ps += p[k]; }
  float inv = 1.f / ps;
  #pragma unroll
  for (int k = 0; k < KSEL; k++) p[k] *= inv;

  float nb[KSEL][8];
  float kaw[KSEL];
  #pragma unroll
  for (int k = 0; k < KSEL; k++) {
    const float* et = ET + (size_t)ti[k] * DIM;
    float snb = 0.f, sg = 0.f;
    #pragma unroll
    for (int u = 0; u < 8; u++) {
      float nbv = et[u * 64 + lane];
      nb[k][u] = nbv;
      float ehr = p[k] * nbv + (1.f - p[k]) * ehv[u];
      float g = tanhf(ehv[u] + ehr);
      snb += nbv; sg += g;
    }
    #pragma unroll
    for (int off = 32; off > 0; off >>= 1) {
      snb += __shfl_xor(snb, off);
      sg  += __shfl_xor(sg, off);
    }
    kaw[k] = snb * sg;
  }
  float km = kaw[0];
  #pragma unroll
  for (int k = 1; k < KSEL; k++) km = fmaxf(km, kaw[k]);
  float kp[KSEL], ks = 0.f;
  #pragma unroll
  for (int k = 0; k < KSEL; k++) { kp[k] = expf(kaw[k] - km); ks += kp[k]; }
  float kinv = 1.f / ks;
  #pragma unroll
  for (int k = 0; k < KSEL; k++) kp[k] *= kinv;

  #pragma unroll
  for (int u = 0; u < 8; u++) {
    float enh = 0.f;
    #pragma unroll
    for (int k = 0; k < KSEL; k++) enh += kp[k] * nb[k][u];
    size_t o = (size_t)row * DIM + u * 64 + lane;
    SINb[o] = f2bf(ehv[u] + enh);
    BINb[o] = f2bf(ehv[u] * enh);
  }
}

__global__ __launch_bounds__(256)
void att2_kernel(const float* __restrict__ HID, const float* __restrict__ w2,
                 const float* __restrict__ b2, float* __restrict__ ASC) {
  const int lane = threadIdx.x & 63;
  const int row = blockIdx.x * 4 + (threadIdx.x >> 6);
  float4 hv = ((const float4*)(HID + (size_t)row * 256))[lane];
  float4 wv = ((const float4*)w2)[lane];
  float s = hv.x * wv.x + hv.y * wv.y + hv.z * wv.z + hv.w * wv.w;
  #pragma unroll
  for (int off = 32; off > 0; off >>= 1) s += __shfl_xor(s, off);
  if (lane == 0) ASC[row] = s + b2[0];
}

__global__ __launch_bounds__(1024)
void areduce(const float* __restrict__ ASC, float* __restrict__ stats) {
  __shared__ float sm[1024];
  int t = threadIdx.x;
  float m = -INFINITY;
  for (int i = t; i < NROWS; i += 1024) m = fmaxf(m, ASC[i]);
  sm[t] = m; __syncthreads();
  for (int s = 512; s > 0; s >>= 1) {
    if (t < s) sm[t] = fmaxf(sm[t], sm[t + s]);
    __syncthreads();
  }
  float mx = sm[0]; __syncthreads();
  float sum = 0.f;
  for (int i = t; i < NROWS; i += 1024) sum += expf(ASC[i] - mx);
  sm[t] = sum; __syncthreads();
  for (int s = 512; s > 0; s >>= 1) {
    if (t < s) sm[t] += sm[t + s];
    __syncthreads();
  }
  if (t == 0) { stats[0] = mx; stats[1] = sm[0]; }
}

__global__ __launch_bounds__(256)
void pooled_partial(const float* __restrict__ EMB, const float* __restrict__ ASC,
                    const float* __restrict__ stats, float* __restrict__ part) {
  int col = blockIdx.x * 64 + (threadIdx.x & 63);
  int sub = threadIdx.x >> 6;
  float mx = stats[0];
  int rEnd = blockIdx.y * 512 + 512;
  float s = 0.f;
  for (int r = blockIdx.y * 512 + sub; r < rEnd; r += 4)
    s += expf(ASC[r] - mx) * EMB[(size_t)r * DIM + col];
  __shared__ float sh[4][64];
  sh[sub][threadIdx.x & 63] = s;
  __syncthreads();
  if (threadIdx.x < 64) {
    float tot = sh[0][threadIdx.x] + sh[1][threadIdx.x] +
                sh[2][threadIdx.x] + sh[3][threadIdx.x];
    part[(size_t)blockIdx.y * DIM + col] = tot;
  }
}

__global__ __launch_bounds__(512)
void final_kernel(const float* __restrict__ part, const float* __restrict__ stats,
                  const float* __restrict__ ln_g, const float* __restrict__ ln_b,
                  const float* __restrict__ fc_w, const float* __restrict__ fc_b,
                  float* __restrict__ out) {
  __shared__ float sh[512];
  int t = threadIdx.x;
  float s = 0.f;
  for (int j = 0; j < 32; j++) s += part[j * DIM + t];
  float pooled = s / stats[1];
  sh[t] = pooled; __syncthreads();
  for (int off = 256; off > 0; off >>= 1) {
    if (t < off) sh[t] += sh[t + off];
    __syncthreads();
  }
  float mu = sh[0] * (1.f / DIM); __syncthreads();
  float dv = pooled - mu;
  sh[t] = dv * dv; __syncthreads();
  for (int off = 256; off > 0; off >>= 1) {
    if (t < off) sh[t] += sh[t + off];
    __syncthreads();
  }
  float var = sh[0] * (1.f / DIM); __syncthreads();
  float normed = dv * rsqrtf(var + 1e-5f) * ln_g[t] + ln_b[t];
  sh[t] = normed * fc_w[t * 2 + 0]; __syncthreads();
  for (int off = 256; off > 0; off >>= 1) {
    if (t < off) sh[t] += sh[t + off];
    __syncthreads();
  }
  float l0 = sh[0] + fc_b[0]; __syncthreads();
  sh[t] = normed * fc_w[t * 2 + 1]; __syncthreads();
  for (int off = 256; off > 0; off >>= 1) {
    if (t < off) sh[t] += sh[t + off];
    __syncthreads();
  }
  float l1 = sh[0] + fc_b[1];
  if (t == 0) {
    float mm = fmaxf(l0, l1);
    float e0 = expf(l0 - mm), e1 = expf(l1 - mm);
    float si = 1.f / (e0 + e1);
    out[0] = l0; out[1] = l1; out[2] = e0 * si; out[3] = e1 * si;
  }
}

// ---------------------------------------------------------------------------
extern "C" void kernel_launch(void* const* d_in, const int* in_sizes, int n_in,
                              void* d_out, int out_size, void* d_ws, size_t ws_size,
                              hipStream_t stream) {
  (void)in_sizes; (void)n_in; (void)out_size; (void)ws_size;
  const float* x      = (const float*)d_in[0];
  const float* fc1_w  = (const float*)d_in[1];
  const float* fc1_b  = (const float*)d_in[2];
  const float* wh_w   = (const float*)d_in[3];
  const float* wh_b   = (const float*)d_in[4];
  const float* wt_w   = (const float*)d_in[5];
  const float* wt_b   = (const float*)d_in[6];
  const float* lin1_w = (const float*)d_in[7];
  const float* lin1_b = (const float*)d_in[8];
  const float* lin2_w = (const float*)d_in[9];
  const float* lin2_b = (const float*)d_in[10];
  const float* att1_w = (const float*)d_in[11];
  const float* att1_b = (const float*)d_in[12];
  const float* att2_w = (const float*)d_in[13];
  const float* att2_b = (const float*)d_in[14];
  const float* ln_g   = (const float*)d_in[15];
  const float* ln_b   = (const float*)d_in[16];
  const float* fc_w   = (const float*)d_in[17];
  const float* fc_b   = (const float*)d_in[18];
  float* out = (float*)d_out;

  char* ws = (char*)d_ws;
  float* B0   = (float*)(ws);                       // h0 -> HID
  float* B1   = (float*)(ws + 33554432);            // [xb] -> e_h
  float* B2   = (float*)(ws + 67108864);            // e_t -> emb
  float* TWp  = (float*)(ws + 100663296);
  int*   TIp  = (int*)  (ws + 100663296 + 1572864);
  float* TW   = (float*)(ws + 100663296 + 3145728);
  int*   TI   = (int*)  (ws + 100663296 + 3145728 + 393216);
  float* part = (float*)(ws + 100663296 + 3145728 + 786432);
  float* mean = (float*)(ws + 100663296 + 3145728 + 786432 + 65536);
  float* ascr = (float*)(ws + 100663296 + 3145728 + 786432 + 65536 + 2048);
  float* stats= (float*)(ws + 100663296 + 3145728 + 786432 + 65536 + 2048 + 65536);
  u16*   hb   = (u16*)(ws + 104732672);             // -> embb
  u16*   EHb  = (u16*)(ws + 104732672 + 16777216);  // -> sinb
  u16*   ETb  = (u16*)(ws + 104732672 + 33554432);  // -> binb
  u16*   WT   = (u16*)(ws + 104732672 + 50331648);  // transposed bf16 weights
  u16* fc1t = WT;
  u16* wht  = fc1t + 196608;
  u16* wtt  = wht + 262144;
  u16* lin1t= wtt + 262144;
  u16* lin2t= lin1t + 262144;
  u16* att1t= lin2t + 262144;
  u16* xb   = (u16*)B1;      // temp in B1 region, dead before e_h written
  u16* sinb = EHb;           // reuse after attn
  u16* binb = ETb;
  u16* embb = hb;

  // 0. input + weight conversions (bf16, weights transposed to [N][K])
  convx<<<3072, 256, 0, stream>>>(x, xb);
  wconv<<<768, 256, 0, stream>>>(fc1_w, fc1t, 384, 512);
  wconv<<<1024, 256, 0, stream>>>(wh_w, wht, 512, 512);
  wconv<<<1024, 256, 0, stream>>>(wt_w, wtt, 512, 512);
  wconv<<<1024, 256, 0, stream>>>(lin1_w, lin1t, 512, 512);
  wconv<<<1024, 256, 0, stream>>>(lin2_w, lin2t, 512, 512);
  wconv<<<512, 256, 0, stream>>>(att1_w, att1t, 512, 256);
  // 1. h0 = lrelu(x @ fc1_w + b)
  gemm_bf16<1,0,0><<<dim3(4,128), 256, 0, stream>>>(xb, fc1t, fc1_b, B0, nullptr, 1.f, 384, 512);
  // 2-4. column mean; hb = bf16((h0+mean)*0.5)
  colsum_partial<<<dim3(8,32), 256, 0, stream>>>(B0, part);
  finalize_mean<<<1, 512, 0, stream>>>(part, mean);
  h_fix_bf<<<4096, 256, 0, stream>>>(B0, mean, hb);
  // 5-6. e_h (f32 + bf16*SCALE), e_t (f32 + bf16)
  gemm_bf16<0,0,1><<<dim3(4,128), 256, 0, stream>>>(hb, wht, wh_b, B1, EHb, ATT_SCALE, 512, 512);
  gemm_bf16<0,0,1><<<dim3(4,128), 256, 0, stream>>>(hb, wtt, wt_b, B2, ETb, 1.f, 512, 512);
  // 7. fused MFMA attn-logit + top-6 per split (shared-B counted-vmcnt), merge
  attn_topk_mfma<<<512, 256, 0, stream>>>(EHb, ETb, TWp, TIp);
  topk_merge<<<64, 256, 0, stream>>>(TWp, TIp, TW, TI);
  // 8. neighbor aggregation -> bf16 s_in / b_in
  neighbor_kernel<<<4096, 256, 0, stream>>>(B1, B2, TW, TI, sinb, binb);
  // 9-10. emb = lrelu(s_in@lin1+b) + lrelu(b_in@lin2+b)  (f32 in B2 + bf16)
  gemm_bf16<1,0,0><<<dim3(4,128), 256, 0, stream>>>(sinb, lin1t, lin1_b, B2, nullptr, 1.f, 512, 512);
  gemm_bf16<1,1,1><<<dim3(4,128), 256, 0, stream>>>(binb, lin2t, lin2_b, B2, embb, 1.f, 512, 512);
  // 11. hidden = lrelu(emb@att1+b) -> B0 f32
  gemm_bf16<1,0,0><<<dim3(2,128), 256, 0, stream>>>(embb, att1t, att1_b, B0, nullptr, 1.f, 512, 256);
  // 12-15. readout
  att2_kernel<<<4096, 256, 0, stream>>>(B0, att2_w, att2_b, ascr);
  areduce<<<1, 1024, 0, stream>>>(ascr, stats);
  pooled_partial<<<dim3(8,32), 256, 0, stream>>>(B2, ascr, stats, part);
  final_kernel<<<1, 512, 0, stream>>>(part, stats, ln_g, ln_b, fc_w, fc_b, out);
}